// Round 3
// baseline (67674.597 us; speedup 1.0000x reference)
//
#include <hip/hip_runtime.h>

#define NB 64
#define NS 512
#define NZ 256
#define NH 1024
#define NWG 256
#define NT 256

typedef _Float16 f16;
typedef __attribute__((ext_vector_type(8))) _Float16 half8;
typedef __attribute__((ext_vector_type(4))) float f32x4;

// ---------------- ws layout (bytes) ----------------
#define WS_OUTP  0          // f16 [128][64][8]  relu output, packed A-frag layout
#define WS_H1P   131072     // f16 [2][128][64][8]
#define WS_H2P   393216     // f16 [2][128][64][8]
#define WS_FLAGS 655360     // unsigned [256][32]  barrier flags, 128B stride
#define WS_WF    1179648    // f16 [1024][1024]  Wfused = W1p @ W2
#define WS_B1P   3276800    // f32 [1024]        b1 + W1p@b2
#define WS_PG0   3280896    // f16 [32][64][8]   packed prev_gen0
// ---------------- LDS layout (bytes) ----------------
#define L_W0   0            // 4 rows x 2576  ([W1z 256h | Wfused 1024h] + 16B pad)
#define L_W2   10304        // 1 row  x 2064  (W2[w] 1024h + pad)
#define L_W1   12368        // 16 rows x 4112 ([Wih1 1024h | Whh1 1024h] + pad)
#define L_WP2  78160        // 16 rows x 4112
#define L_W1P  143952       // 4 rows x 528   (W1p 256h + pad) for t==0
#define L_X    146064       // 4 waves x 1024B exchange scratch
#define LDS_BYTES 150160

__device__ __forceinline__ float sigf(float x) { return 1.f / (1.f + __expf(-x)); }
__device__ __forceinline__ float tanhfast(float x) { return 2.f / (1.f + __expf(-2.f * x)) - 1.f; }

__device__ __forceinline__ f32x4 MF(half8 a, half8 b, f32x4 c) {
  return __builtin_amdgcn_mfma_f32_16x16x32_f16(a, b, c, 0, 0, 0);
}

// -------- distributed flag barrier (split arrive/wait), monotonic epochs --------
__device__ __forceinline__ void bar_arrive(unsigned* flags, int w, unsigned e) {
  __syncthreads();                      // all waves' stores issued
  if (threadIdx.x == 0) {
    __threadfence();                    // agent-scope release of phase data
    __hip_atomic_store(flags + (size_t)w * 32, e, __ATOMIC_RELEASE, __HIP_MEMORY_SCOPE_AGENT);
  }
}
__device__ __forceinline__ void bar_wait(unsigned* flags, unsigned e) {
  unsigned* slot = flags + (size_t)threadIdx.x * 32;   // NT == NWG == 256
  int ok = (__hip_atomic_load(slot, __ATOMIC_ACQUIRE, __HIP_MEMORY_SCOPE_AGENT) >= e);
  while (!__syncthreads_and(ok)) {
    ok = (__hip_atomic_load(slot, __ATOMIC_ACQUIRE, __HIP_MEMORY_SCOPE_AGENT) >= e);
  }
  __threadfence();                      // acquire: order subsequent data loads
}

__global__ void init_state(const float* __restrict__ h1, const float* __restrict__ h2,
                           const float* __restrict__ pg0, const float* __restrict__ W1,
                           const float* __restrict__ b1, const float* __restrict__ b2,
                           char* __restrict__ ws) {
  int i = blockIdx.x * blockDim.x + threadIdx.x;  // 0..65535
  int R = i & 63;
  int U = i >> 6;
  f16* H1p = (f16*)(ws + WS_H1P);
  f16* H2p = (f16*)(ws + WS_H2P);
  int pidx = ((U >> 3) * 64 + R) * 8 + (U & 7);
  H1p[pidx] = (f16)h1[(size_t)R * NH + U];   // parity-0 buffer
  H2p[pidx] = (f16)h2[(size_t)R * NH + U];
  if (i < 16384) {  // pack prev_gen0: u in 0..255
    int u = i >> 6, r2 = i & 63;
    ((f16*)(ws + WS_PG0))[((u >> 3) * 64 + r2) * 8 + (u & 7)] = (f16)pg0[(size_t)r2 * NZ + u];
  }
  if (i < NH) {  // b1p = b1 + W1p @ b2
    float acc = b1[i];
    const float* wp = W1 + (size_t)i * (2 * NZ) + NZ;
    for (int mm = 0; mm < NZ; ++mm) acc = fmaf(wp[mm], b2[mm], acc);
    ((float*)(ws + WS_B1P))[i] = acc;
  }
  if (i < 8192) ((unsigned*)(ws + WS_FLAGS))[i] = 0u;
}

__global__ void prep_wfused(const float* __restrict__ W1, const float* __restrict__ W2,
                            char* __restrict__ ws) {
  int u = blockIdx.x >> 2;
  int j = ((blockIdx.x & 3) << 8) + threadIdx.x;
  const float* wp = W1 + (size_t)u * (2 * NZ) + NZ;
  float acc = 0.f;
  for (int mm = 0; mm < NZ; ++mm) acc = fmaf(wp[mm], W2[(size_t)mm * NH + j], acc);
  ((f16*)(ws + WS_WF))[(size_t)u * NH + j] = (f16)acc;
}

__global__ __launch_bounds__(NT, 1) void gen_persistent(
    const float* __restrict__ z,
    const float* __restrict__ W1, const float* __restrict__ b1,
    const float* __restrict__ Wih1, const float* __restrict__ Whh1,
    const float* __restrict__ bih1, const float* __restrict__ bhh1,
    const float* __restrict__ Wih2, const float* __restrict__ Whh2,
    const float* __restrict__ bih2, const float* __restrict__ bhh2,
    const float* __restrict__ W2, const float* __restrict__ b2,
    const float* __restrict__ c1in, const float* __restrict__ c2in,
    float* __restrict__ dout, char* __restrict__ ws)
{
  extern __shared__ char smem[];
  const int w = blockIdx.x;
  const int tid = threadIdx.x;
  const int m = tid >> 6;      // wave -> batch rows 16m..16m+15
  const int l = tid & 63;
  const int c = l & 15;        // MFMA col / A-row-within-16
  const int kg = l >> 4;       // k-group

  f16* OutP = (f16*)(ws + WS_OUTP);
  f16* H1p = (f16*)(ws + WS_H1P);
  f16* H2p = (f16*)(ws + WS_H2P);
  const f16* Wf = (const f16*)(ws + WS_WF);
  const f16* Pg0p = (const f16*)(ws + WS_PG0);
  const float* b1p = (const float*)(ws + WS_B1P);
  unsigned* flags = (unsigned*)(ws + WS_FLAGS);

  // ---- load this CU's weight slices into LDS (fp32 -> fp16), once ----
  for (int i = 0; i < 16; ++i) {
    int gi = i >> 2, uu = 4 * w + (i & 3);
    const float* s1i = Wih1 + (size_t)(gi * NH + uu) * NH;
    const float* s1h = Whh1 + (size_t)(gi * NH + uu) * NH;
    const float* s2i = Wih2 + (size_t)(gi * NH + uu) * NH;
    const float* s2h = Whh2 + (size_t)(gi * NH + uu) * NH;
    f16* d1 = (f16*)(smem + L_W1 + i * 4112);
    f16* d2 = (f16*)(smem + L_WP2 + i * 4112);
    for (int k = tid; k < NH; k += NT) {
      d1[k] = (f16)s1i[k]; d1[NH + k] = (f16)s1h[k];
      d2[k] = (f16)s2i[k]; d2[NH + k] = (f16)s2h[k];
    }
  }
  for (int i = 0; i < 4; ++i) {
    int uu = 4 * w + i;
    f16* d0 = (f16*)(smem + L_W0 + i * 2576);
    d0[tid] = (f16)W1[(size_t)uu * (2 * NZ) + tid];           // z part (256 = NT)
    for (int k = tid; k < NH; k += NT) d0[NZ + k] = Wf[(size_t)uu * NH + k];
    f16* dp = (f16*)(smem + L_W1P + i * 528);
    dp[tid] = (f16)W1[(size_t)uu * (2 * NZ) + NZ + tid];      // W1p part for t==0
  }
  {
    f16* dw2 = (f16*)(smem + L_W2);
    for (int k = tid; k < NH; k += NT) dw2[k] = (f16)W2[(size_t)w * NH + k];
  }
  __syncthreads();

  const int R = 16 * m + c;          // batch row
  const int U = 4 * w + kg;          // owned unit
  const int hpack = ((U >> 3) * 64 + R) * 8 + (U & 7);
  const float b0fused = b1p[U];
  const float b0plain = b1[U];
  const float bi1 = bih1[U] + bhh1[U];
  const float bf1 = bih1[NH + U] + bhh1[NH + U];
  const float bg1 = bih1[2 * NH + U] + bhh1[2 * NH + U];
  const float bo1 = bih1[3 * NH + U] + bhh1[3 * NH + U];
  const float bi2 = bih2[U] + bhh2[U];
  const float bf2 = bih2[NH + U] + bhh2[NH + U];
  const float bg2 = bih2[2 * NH + U] + bhh2[2 * NH + U];
  const float bo2 = bih2[3 * NH + U] + bhh2[3 * NH + U];
  const float b2w = b2[w];

  // cell states live in registers: this thread is the only reader/writer of (U,R)
  float c1reg = c1in[(size_t)R * NH + U];
  float c2reg = c2in[(size_t)R * NH + U];
  float h1last = 0.f, h2last = 0.f;

  float* scr = (float*)(smem + L_X) + m * 256;
  const char* brow0 = smem + L_W0 + (c & 3) * 2576 + kg * 16;
  const char* brow2 = smem + L_W2 + kg * 16;
  const char* brow1 = smem + L_W1 + c * 4112 + kg * 16;
  const char* browp2 = smem + L_WP2 + c * 4112 + kg * 16;
  const char* browp0 = smem + L_W1P + (c & 3) * 528 + kg * 16;
  const float* zlane = z + (size_t)R * NS * NZ + kg * 8;

  for (int t = 0; t < NS; ++t) {
    const int par = t & 1;
    const f16* h2prev = H2p + par * 65536;
    const f16* h1prev = H1p + par * 65536;
    const unsigned eb = 3u * (unsigned)t;

    // ================= P0 =================
    // ---- ind0: z-part (+ pg0 path at t==0) — does not need the barrier ----
    f32x4 ao0 = {0.f, 0.f, 0.f, 0.f}, ao1 = ao0, ap0 = ao0, ap1 = ao0;
    {
      const float* zt = zlane + (size_t)t * NZ;
      #pragma unroll
      for (int kk = 0; kk < 8; ++kk) {
        f32x4 f0 = *(const f32x4*)(zt + kk * 32);
        f32x4 f1 = *(const f32x4*)(zt + kk * 32 + 4);
        half8 a;
        a[0] = (f16)f0[0]; a[1] = (f16)f0[1]; a[2] = (f16)f0[2]; a[3] = (f16)f0[3];
        a[4] = (f16)f1[0]; a[5] = (f16)f1[1]; a[6] = (f16)f1[2]; a[7] = (f16)f1[3];
        half8 b = *(const half8*)(brow0 + kk * 64);
        if (kk & 1) ao1 = MF(a, b, ao1); else ao0 = MF(a, b, ao0);
      }
      if (t == 0) {
        #pragma unroll
        for (int kk = 0; kk < 8; ++kk) {
          half8 a = *(const half8*)(Pg0p + (((4 * kk + kg) * 64 + R) << 3));
          half8 b = *(const half8*)(browp0 + kk * 64);
          if (kk & 1) ao1 = MF(a, b, ao1); else ao0 = MF(a, b, ao0);
        }
      }
    }
    // ---- wait for h2prev (written before arrival eb) ----
    bar_wait(flags, eb);
    // ---- dep0: h2prev @ [Wfused | W2] ----
    if (t > 0) {
      #pragma unroll 8
      for (int kk = 0; kk < 32; ++kk) {
        half8 a = *(const half8*)(h2prev + (((4 * kk + kg) * 64 + R) << 3));
        half8 bwf = *(const half8*)(brow0 + 512 + kk * 64);
        half8 bw2 = *(const half8*)(brow2 + kk * 64);
        if (kk & 1) { ao1 = MF(a, bwf, ao1); ap1 = MF(a, bw2, ap1); }
        else        { ao0 = MF(a, bwf, ao0); ap0 = MF(a, bw2, ap0); }
      }
    }
    {
      f32x4 D = ao0 + ao1;
      if (c < 4) {
        #pragma unroll
        for (int v = 0; v < 4; ++v) scr[c * 16 + kg * 4 + v] = D[v];
      }
      float pre = scr[kg * 16 + c] + ((t == 0) ? b0plain : b0fused);
      OutP[hpack] = (f16)fmaxf(pre, 0.f);
    }
    bar_arrive(flags, w, eb + 1);
    // deferred lazy pg(t-1) store — pure output, overlapped with others' waits
    if (t > 0 && c == 0) {
      f32x4 Dp = ap0 + ap1;
      #pragma unroll
      for (int v = 0; v < 4; ++v) {
        int Rp = 16 * m + kg * 4 + v;
        dout[((size_t)Rp * NS + (t - 1)) * NZ + w] = Dp[v] + b2w;
      }
    }

    // ================= P1 =================
    f32x4 g0 = {0.f, 0.f, 0.f, 0.f}, g1 = g0;
    // ---- ind1: h1prev @ Whh1 (h1prev is one step old — already visible) ----
    #pragma unroll 8
    for (int kk = 0; kk < 32; ++kk) {
      half8 a = *(const half8*)(h1prev + (((4 * kk + kg) * 64 + R) << 3));
      half8 b = *(const half8*)(brow1 + 2048 + kk * 64);
      if (kk & 1) g1 = MF(a, b, g1); else g0 = MF(a, b, g0);
    }
    bar_wait(flags, eb + 1);
    // ---- dep1: out @ Wih1 ----
    #pragma unroll 8
    for (int kk = 0; kk < 32; ++kk) {
      half8 a = *(const half8*)(OutP + (((4 * kk + kg) * 64 + R) << 3));
      half8 b = *(const half8*)(brow1 + kk * 64);
      if (kk & 1) g1 = MF(a, b, g1); else g0 = MF(a, b, g0);
    }
    {
      f32x4 D = g0 + g1;
      #pragma unroll
      for (int v = 0; v < 4; ++v) scr[c * 16 + kg * 4 + v] = D[v];
      float ai = scr[kg * 16 + c];
      float af = scr[(4 + kg) * 16 + c];
      float ag = scr[(8 + kg) * 16 + c];
      float aoo = scr[(12 + kg) * 16 + c];
      float iv = sigf(ai + bi1), fv = sigf(af + bf1);
      float gv = tanhfast(ag + bg1), ov = sigf(aoo + bo1);
      float cn = fmaf(fv, c1reg, iv * gv);
      c1reg = cn;
      float hv = ov * tanhfast(cn);
      h1last = hv;
      H1p[(par ^ 1) * 65536 + hpack] = (f16)hv;
    }
    bar_arrive(flags, w, eb + 2);

    // ================= P2 =================
    f32x4 q0 = {0.f, 0.f, 0.f, 0.f}, q1 = q0;
    // ---- ind2: h2prev @ Whh2 ----
    #pragma unroll 8
    for (int kk = 0; kk < 32; ++kk) {
      half8 a = *(const half8*)(h2prev + (((4 * kk + kg) * 64 + R) << 3));
      half8 b = *(const half8*)(browp2 + 2048 + kk * 64);
      if (kk & 1) q1 = MF(a, b, q1); else q0 = MF(a, b, q0);
    }
    bar_wait(flags, eb + 2);
    // ---- dep2: h1new @ Wih2 ----
    {
      const f16* h1new = H1p + (par ^ 1) * 65536;
      #pragma unroll 8
      for (int kk = 0; kk < 32; ++kk) {
        half8 a = *(const half8*)(h1new + (((4 * kk + kg) * 64 + R) << 3));
        half8 b = *(const half8*)(browp2 + kk * 64);
        if (kk & 1) q1 = MF(a, b, q1); else q0 = MF(a, b, q0);
      }
    }
    {
      f32x4 D = q0 + q1;
      #pragma unroll
      for (int v = 0; v < 4; ++v) scr[c * 16 + kg * 4 + v] = D[v];
      float ai = scr[kg * 16 + c];
      float af = scr[(4 + kg) * 16 + c];
      float ag = scr[(8 + kg) * 16 + c];
      float aoo = scr[(12 + kg) * 16 + c];
      float iv = sigf(ai + bi2), fv = sigf(af + bf2);
      float gv = tanhfast(ag + bg2), ov = sigf(aoo + bo2);
      float cn = fmaf(fv, c2reg, iv * gv);
      c2reg = cn;
      float hv = ov * tanhfast(cn);
      h2last = hv;
      H2p[(par ^ 1) * 65536 + hpack] = (f16)hv;
    }
    bar_arrive(flags, w, eb + 3);
  }

  // ---------- tail: pg for t=511 from final h2 (parity 0) ----------
  bar_wait(flags, 3u * NS);
  {
    f32x4 ap0 = {0.f, 0.f, 0.f, 0.f}, ap1 = ap0;
    #pragma unroll 8
    for (int kk = 0; kk < 32; ++kk) {
      half8 a = *(const half8*)(H2p + (((4 * kk + kg) * 64 + R) << 3));
      half8 b = *(const half8*)(brow2 + kk * 64);
      if (kk & 1) ap1 = MF(a, b, ap1); else ap0 = MF(a, b, ap0);
    }
    if (c == 0) {
      f32x4 Dp = ap0 + ap1;
      #pragma unroll
      for (int v = 0; v < 4; ++v) {
        int Rp = 16 * m + kg * 4 + v;
        dout[((size_t)Rp * NS + (NS - 1)) * NZ + w] = Dp[v] + b2w;
      }
    }
  }

  // ---------- final states (own (U,R) values, all in registers) ----------
  {
    float* o = dout + (size_t)NB * NS * NZ;
    o[(size_t)R * NH + U] = h1last;
    o[(size_t)NB * NH + (size_t)R * NH + U] = c1reg;
    o[2 * (size_t)NB * NH + (size_t)R * NH + U] = h2last;
    o[3 * (size_t)NB * NH + (size_t)R * NH + U] = c2reg;
  }
}

extern "C" void kernel_launch(void* const* d_in, const int* in_sizes, int n_in,
                              void* d_out, int out_size, void* d_ws, size_t ws_size,
                              hipStream_t stream) {
  const float* z    = (const float*)d_in[0];
  const float* pg0  = (const float*)d_in[1];
  const float* h1   = (const float*)d_in[2];
  const float* c1   = (const float*)d_in[3];
  const float* h2   = (const float*)d_in[4];
  const float* c2   = (const float*)d_in[5];
  const float* W1   = (const float*)d_in[6];
  const float* b1   = (const float*)d_in[7];
  const float* Wih1 = (const float*)d_in[8];
  const float* Whh1 = (const float*)d_in[9];
  const float* bih1 = (const float*)d_in[10];
  const float* bhh1 = (const float*)d_in[11];
  const float* Wih2 = (const float*)d_in[12];
  const float* Whh2 = (const float*)d_in[13];
  const float* bih2 = (const float*)d_in[14];
  const float* bhh2 = (const float*)d_in[15];
  const float* W2   = (const float*)d_in[16];
  const float* b2   = (const float*)d_in[17];
  char* ws = (char*)d_ws;
  float* out = (float*)d_out;

  hipLaunchKernelGGL(init_state, dim3(256), dim3(256), 0, stream,
                     h1, h2, pg0, W1, b1, b2, ws);
  hipLaunchKernelGGL(prep_wfused, dim3(4096), dim3(256), 0, stream, W1, W2, ws);
  hipLaunchKernelGGL(gen_persistent, dim3(NWG), dim3(NT), LDS_BYTES, stream,
                     z, W1, b1, Wih1, Whh1, bih1, bhh1, Wih2, Whh2, bih2, bhh2, W2, b2,
                     c1, c2, out, ws);
}

// Round 4
// 41304.202 us; speedup vs baseline: 1.6384x; 1.6384x over previous
//
#include <hip/hip_runtime.h>

#define NB 64
#define NS 512
#define NZ 256
#define NH 1024
#define NWG 256
#define NT 256

typedef _Float16 f16;
typedef __attribute__((ext_vector_type(8))) _Float16 half8;
typedef __attribute__((ext_vector_type(4))) float f32x4;

// ---------------- ws layout (bytes) ----------------
#define WS_OUTP  0          // f16 [128][64][8]  relu output, packed A-frag layout
#define WS_H1P   131072     // f16 [2][128][64][8]
#define WS_H2P   393216     // f16 [2][128][64][8]
#define WS_BAR   655360     // barrier: L1[16] @+g*128, root @+2048, flag[8] @+4096+i*128
#define WS_WF    1179648    // f16 [1024][1024]  Wfused = W1p @ W2
#define WS_B1P   3276800    // f32 [1024]        b1 + W1p@b2
#define WS_PG0   3280896    // f16 [32][64][8]   packed prev_gen0
// ---------------- LDS layout (bytes) ----------------
#define L_W0   0            // 4 rows x 2576  ([W1z 256h | Wfused 1024h] + 16B pad)
#define L_W2   10304        // 1 row  x 2064  (W2[w] 1024h + pad)
#define L_W1   12368        // 16 rows x 4112 ([Wih1 1024h | Whh1 1024h] + pad)
#define L_WP2  78160        // 16 rows x 4112
#define L_W1P  143952       // 4 rows x 528   (W1p 256h + pad) for t==0
#define L_X    146064       // 4 waves x 1024B exchange scratch
#define LDS_BYTES 150160

__device__ __forceinline__ float sigf(float x) { return 1.f / (1.f + __expf(-x)); }
__device__ __forceinline__ float tanhfast(float x) { return 2.f / (1.f + __expf(-2.f * x)) - 1.f; }

__device__ __forceinline__ f32x4 MF(half8 a, half8 b, f32x4 c) {
  return __builtin_amdgcn_mfma_f32_16x16x32_f16(a, b, c, 0, 0, 0);
}

// -------- hierarchical tree barrier: 16x16 arrival tree, 8 replicated flag lines --------
// Arrival (tid 0 only): L1[w>>4] fetch_add; 16th arriver forwards to root; root's 16th
// forward publishes epoch to 8 flag replicas. All counters monotonic (no reset).
__device__ __forceinline__ void bar_arrive(char* bar, int w) {
  __syncthreads();                      // all waves' data stores issued
  if (threadIdx.x == 0) {
    __threadfence();                    // agent-scope release of phase data
    unsigned* l1 = (unsigned*)(bar + (size_t)(w >> 4) * 128);
    unsigned p1 = __hip_atomic_fetch_add(l1, 1u, __ATOMIC_ACQ_REL, __HIP_MEMORY_SCOPE_AGENT);
    if (((p1 + 1u) & 15u) == 0u) {      // group of 16 complete for this epoch
      unsigned* root = (unsigned*)(bar + 2048);
      unsigned p2 = __hip_atomic_fetch_add(root, 1u, __ATOMIC_ACQ_REL, __HIP_MEMORY_SCOPE_AGENT);
      if (((p2 + 1u) & 15u) == 0u) {    // all 16 groups forwarded -> epoch done
        unsigned e = (p2 + 1u) >> 4;
        #pragma unroll
        for (int i = 0; i < 8; ++i)
          __hip_atomic_store((unsigned*)(bar + 4096 + i * 128), e,
                             __ATOMIC_RELEASE, __HIP_MEMORY_SCOPE_AGENT);
      }
    }
  }
}
__device__ __forceinline__ void bar_wait(char* bar, int w, unsigned e) {
  if (threadIdx.x == 0) {
    unsigned* f = (unsigned*)(bar + 4096 + (size_t)(w & 7) * 128);  // 32 WGs per replica
    while (__hip_atomic_load(f, __ATOMIC_ACQUIRE, __HIP_MEMORY_SCOPE_AGENT) < e)
      __builtin_amdgcn_s_sleep(1);
  }
  __syncthreads();
}

__global__ void init_state(const float* __restrict__ h1, const float* __restrict__ h2,
                           const float* __restrict__ pg0, const float* __restrict__ W1,
                           const float* __restrict__ b1, const float* __restrict__ b2,
                           char* __restrict__ ws) {
  int i = blockIdx.x * blockDim.x + threadIdx.x;  // 0..65535
  int R = i & 63;
  int U = i >> 6;
  f16* H1p = (f16*)(ws + WS_H1P);
  f16* H2p = (f16*)(ws + WS_H2P);
  int pidx = ((U >> 3) * 64 + R) * 8 + (U & 7);
  H1p[pidx] = (f16)h1[(size_t)R * NH + U];   // parity-0 buffer
  H2p[pidx] = (f16)h2[(size_t)R * NH + U];
  if (i < 16384) {  // pack prev_gen0: u in 0..255
    int u = i >> 6, r2 = i & 63;
    ((f16*)(ws + WS_PG0))[((u >> 3) * 64 + r2) * 8 + (u & 7)] = (f16)pg0[(size_t)r2 * NZ + u];
  }
  if (i < NH) {  // b1p = b1 + W1p @ b2
    float acc = b1[i];
    const float* wp = W1 + (size_t)i * (2 * NZ) + NZ;
    for (int mm = 0; mm < NZ; ++mm) acc = fmaf(wp[mm], b2[mm], acc);
    ((float*)(ws + WS_B1P))[i] = acc;
  }
  if (i < 8192) ((unsigned*)(ws + WS_BAR))[i] = 0u;  // counters + flags
}

__global__ void prep_wfused(const float* __restrict__ W1, const float* __restrict__ W2,
                            char* __restrict__ ws) {
  int u = blockIdx.x >> 2;
  int j = ((blockIdx.x & 3) << 8) + threadIdx.x;
  const float* wp = W1 + (size_t)u * (2 * NZ) + NZ;
  float acc = 0.f;
  for (int mm = 0; mm < NZ; ++mm) acc = fmaf(wp[mm], W2[(size_t)mm * NH + j], acc);
  ((f16*)(ws + WS_WF))[(size_t)u * NH + j] = (f16)acc;
}

__global__ __launch_bounds__(NT, 1) void gen_persistent(
    const float* __restrict__ z,
    const float* __restrict__ W1, const float* __restrict__ b1,
    const float* __restrict__ Wih1, const float* __restrict__ Whh1,
    const float* __restrict__ bih1, const float* __restrict__ bhh1,
    const float* __restrict__ Wih2, const float* __restrict__ Whh2,
    const float* __restrict__ bih2, const float* __restrict__ bhh2,
    const float* __restrict__ W2, const float* __restrict__ b2,
    const float* __restrict__ c1in, const float* __restrict__ c2in,
    float* __restrict__ dout, char* __restrict__ ws)
{
  extern __shared__ char smem[];
  const int w = blockIdx.x;
  const int tid = threadIdx.x;
  const int m = tid >> 6;      // wave -> batch rows 16m..16m+15
  const int l = tid & 63;
  const int c = l & 15;        // MFMA col / A-row-within-16
  const int kg = l >> 4;       // k-group

  f16* OutP = (f16*)(ws + WS_OUTP);
  f16* H1p = (f16*)(ws + WS_H1P);
  f16* H2p = (f16*)(ws + WS_H2P);
  const f16* Wf = (const f16*)(ws + WS_WF);
  const f16* Pg0p = (const f16*)(ws + WS_PG0);
  const float* b1p = (const float*)(ws + WS_B1P);
  char* bar = ws + WS_BAR;

  // ---- load this CU's weight slices into LDS (fp32 -> fp16), once ----
  for (int i = 0; i < 16; ++i) {
    int gi = i >> 2, uu = 4 * w + (i & 3);
    const float* s1i = Wih1 + (size_t)(gi * NH + uu) * NH;
    const float* s1h = Whh1 + (size_t)(gi * NH + uu) * NH;
    const float* s2i = Wih2 + (size_t)(gi * NH + uu) * NH;
    const float* s2h = Whh2 + (size_t)(gi * NH + uu) * NH;
    f16* d1 = (f16*)(smem + L_W1 + i * 4112);
    f16* d2 = (f16*)(smem + L_WP2 + i * 4112);
    for (int k = tid; k < NH; k += NT) {
      d1[k] = (f16)s1i[k]; d1[NH + k] = (f16)s1h[k];
      d2[k] = (f16)s2i[k]; d2[NH + k] = (f16)s2h[k];
    }
  }
  for (int i = 0; i < 4; ++i) {
    int uu = 4 * w + i;
    f16* d0 = (f16*)(smem + L_W0 + i * 2576);
    d0[tid] = (f16)W1[(size_t)uu * (2 * NZ) + tid];           // z part (256 = NT)
    for (int k = tid; k < NH; k += NT) d0[NZ + k] = Wf[(size_t)uu * NH + k];
    f16* dp = (f16*)(smem + L_W1P + i * 528);
    dp[tid] = (f16)W1[(size_t)uu * (2 * NZ) + NZ + tid];      // W1p part for t==0
  }
  {
    f16* dw2 = (f16*)(smem + L_W2);
    for (int k = tid; k < NH; k += NT) dw2[k] = (f16)W2[(size_t)w * NH + k];
  }
  __syncthreads();

  const int R = 16 * m + c;          // batch row
  const int U = 4 * w + kg;          // owned unit
  const int hpack = ((U >> 3) * 64 + R) * 8 + (U & 7);
  const float b0fused = b1p[U];
  const float b0plain = b1[U];
  const float bi1 = bih1[U] + bhh1[U];
  const float bf1 = bih1[NH + U] + bhh1[NH + U];
  const float bg1 = bih1[2 * NH + U] + bhh1[2 * NH + U];
  const float bo1 = bih1[3 * NH + U] + bhh1[3 * NH + U];
  const float bi2 = bih2[U] + bhh2[U];
  const float bf2 = bih2[NH + U] + bhh2[NH + U];
  const float bg2 = bih2[2 * NH + U] + bhh2[2 * NH + U];
  const float bo2 = bih2[3 * NH + U] + bhh2[3 * NH + U];
  const float b2w = b2[w];

  // cell states live in registers: this thread is the only reader/writer of (U,R)
  float c1reg = c1in[(size_t)R * NH + U];
  float c2reg = c2in[(size_t)R * NH + U];
  float h1last = 0.f, h2last = 0.f;

  float* scr = (float*)(smem + L_X) + m * 256;
  const char* brow0 = smem + L_W0 + (c & 3) * 2576 + kg * 16;
  const char* brow2 = smem + L_W2 + kg * 16;
  const char* brow1 = smem + L_W1 + c * 4112 + kg * 16;
  const char* browp2 = smem + L_WP2 + c * 4112 + kg * 16;
  const char* browp0 = smem + L_W1P + (c & 3) * 528 + kg * 16;
  const float* zlane = z + (size_t)R * NS * NZ + kg * 8;

  for (int t = 0; t < NS; ++t) {
    const int par = t & 1;
    const f16* h2prev = H2p + par * 65536;
    const f16* h1prev = H1p + par * 65536;
    const unsigned eb = 3u * (unsigned)t;

    // ================= P0 =================
    // ---- ind0: z-part (+ pg0 path at t==0) — does not need the barrier ----
    f32x4 ao0 = {0.f, 0.f, 0.f, 0.f}, ao1 = ao0, ap0 = ao0, ap1 = ao0;
    {
      const float* zt = zlane + (size_t)t * NZ;
      #pragma unroll
      for (int kk = 0; kk < 8; ++kk) {
        f32x4 f0 = *(const f32x4*)(zt + kk * 32);
        f32x4 f1 = *(const f32x4*)(zt + kk * 32 + 4);
        half8 a;
        a[0] = (f16)f0[0]; a[1] = (f16)f0[1]; a[2] = (f16)f0[2]; a[3] = (f16)f0[3];
        a[4] = (f16)f1[0]; a[5] = (f16)f1[1]; a[6] = (f16)f1[2]; a[7] = (f16)f1[3];
        half8 b = *(const half8*)(brow0 + kk * 64);
        if (kk & 1) ao1 = MF(a, b, ao1); else ao0 = MF(a, b, ao0);
      }
      if (t == 0) {
        #pragma unroll
        for (int kk = 0; kk < 8; ++kk) {
          half8 a = *(const half8*)(Pg0p + (((4 * kk + kg) * 64 + R) << 3));
          half8 b = *(const half8*)(browp0 + kk * 64);
          if (kk & 1) ao1 = MF(a, b, ao1); else ao0 = MF(a, b, ao0);
        }
      }
    }
    // ---- wait for h2prev (epoch 3t = P2 of step t-1) ----
    bar_wait(bar, w, eb);
    // ---- dep0: h2prev @ [Wfused | W2] ----
    if (t > 0) {
      #pragma unroll 8
      for (int kk = 0; kk < 32; ++kk) {
        half8 a = *(const half8*)(h2prev + (((4 * kk + kg) * 64 + R) << 3));
        half8 bwf = *(const half8*)(brow0 + 512 + kk * 64);
        half8 bw2 = *(const half8*)(brow2 + kk * 64);
        if (kk & 1) { ao1 = MF(a, bwf, ao1); ap1 = MF(a, bw2, ap1); }
        else        { ao0 = MF(a, bwf, ao0); ap0 = MF(a, bw2, ap0); }
      }
    }
    {
      f32x4 D = ao0 + ao1;
      if (c < 4) {
        #pragma unroll
        for (int v = 0; v < 4; ++v) scr[c * 16 + kg * 4 + v] = D[v];
      }
      float pre = scr[kg * 16 + c] + ((t == 0) ? b0plain : b0fused);
      OutP[hpack] = (f16)fmaxf(pre, 0.f);
    }
    bar_arrive(bar, w);   // completes epoch 3t+1
    // deferred lazy pg(t-1) store — pure output, overlapped with others' waits
    if (t > 0 && c == 0) {
      f32x4 Dp = ap0 + ap1;
      #pragma unroll
      for (int v = 0; v < 4; ++v) {
        int Rp = 16 * m + kg * 4 + v;
        dout[((size_t)Rp * NS + (t - 1)) * NZ + w] = Dp[v] + b2w;
      }
    }

    // ================= P1 =================
    f32x4 g0 = {0.f, 0.f, 0.f, 0.f}, g1 = g0;
    // ---- ind1: h1prev @ Whh1 (one step old — already visible) ----
    #pragma unroll 8
    for (int kk = 0; kk < 32; ++kk) {
      half8 a = *(const half8*)(h1prev + (((4 * kk + kg) * 64 + R) << 3));
      half8 b = *(const half8*)(brow1 + 2048 + kk * 64);
      if (kk & 1) g1 = MF(a, b, g1); else g0 = MF(a, b, g0);
    }
    bar_wait(bar, w, eb + 1);
    // ---- dep1: out @ Wih1 ----
    #pragma unroll 8
    for (int kk = 0; kk < 32; ++kk) {
      half8 a = *(const half8*)(OutP + (((4 * kk + kg) * 64 + R) << 3));
      half8 b = *(const half8*)(brow1 + kk * 64);
      if (kk & 1) g1 = MF(a, b, g1); else g0 = MF(a, b, g0);
    }
    {
      f32x4 D = g0 + g1;
      #pragma unroll
      for (int v = 0; v < 4; ++v) scr[c * 16 + kg * 4 + v] = D[v];
      float ai = scr[kg * 16 + c];
      float af = scr[(4 + kg) * 16 + c];
      float ag = scr[(8 + kg) * 16 + c];
      float aoo = scr[(12 + kg) * 16 + c];
      float iv = sigf(ai + bi1), fv = sigf(af + bf1);
      float gv = tanhfast(ag + bg1), ov = sigf(aoo + bo1);
      float cn = fmaf(fv, c1reg, iv * gv);
      c1reg = cn;
      float hv = ov * tanhfast(cn);
      h1last = hv;
      H1p[(par ^ 1) * 65536 + hpack] = (f16)hv;
    }
    bar_arrive(bar, w);   // completes epoch 3t+2

    // ================= P2 =================
    f32x4 q0 = {0.f, 0.f, 0.f, 0.f}, q1 = q0;
    // ---- ind2: h2prev @ Whh2 ----
    #pragma unroll 8
    for (int kk = 0; kk < 32; ++kk) {
      half8 a = *(const half8*)(h2prev + (((4 * kk + kg) * 64 + R) << 3));
      half8 b = *(const half8*)(browp2 + 2048 + kk * 64);
      if (kk & 1) q1 = MF(a, b, q1); else q0 = MF(a, b, q0);
    }
    bar_wait(bar, w, eb + 2);
    // ---- dep2: h1new @ Wih2 ----
    {
      const f16* h1new = H1p + (par ^ 1) * 65536;
      #pragma unroll 8
      for (int kk = 0; kk < 32; ++kk) {
        half8 a = *(const half8*)(h1new + (((4 * kk + kg) * 64 + R) << 3));
        half8 b = *(const half8*)(browp2 + kk * 64);
        if (kk & 1) q1 = MF(a, b, q1); else q0 = MF(a, b, q0);
      }
    }
    {
      f32x4 D = q0 + q1;
      #pragma unroll
      for (int v = 0; v < 4; ++v) scr[c * 16 + kg * 4 + v] = D[v];
      float ai = scr[kg * 16 + c];
      float af = scr[(4 + kg) * 16 + c];
      float ag = scr[(8 + kg) * 16 + c];
      float aoo = scr[(12 + kg) * 16 + c];
      float iv = sigf(ai + bi2), fv = sigf(af + bf2);
      float gv = tanhfast(ag + bg2), ov = sigf(aoo + bo2);
      float cn = fmaf(fv, c2reg, iv * gv);
      c2reg = cn;
      float hv = ov * tanhfast(cn);
      h2last = hv;
      H2p[(par ^ 1) * 65536 + hpack] = (f16)hv;
    }
    bar_arrive(bar, w);   // completes epoch 3t+3
  }

  // ---------- tail: pg for t=511 from final h2 (parity 0) ----------
  bar_wait(bar, w, 3u * NS);
  {
    f32x4 ap0 = {0.f, 0.f, 0.f, 0.f}, ap1 = ap0;
    #pragma unroll 8
    for (int kk = 0; kk < 32; ++kk) {
      half8 a = *(const half8*)(H2p + (((4 * kk + kg) * 64 + R) << 3));
      half8 b = *(const half8*)(brow2 + kk * 64);
      if (kk & 1) ap1 = MF(a, b, ap1); else ap0 = MF(a, b, ap0);
    }
    if (c == 0) {
      f32x4 Dp = ap0 + ap1;
      #pragma unroll
      for (int v = 0; v < 4; ++v) {
        int Rp = 16 * m + kg * 4 + v;
        dout[((size_t)Rp * NS + (NS - 1)) * NZ + w] = Dp[v] + b2w;
      }
    }
  }

  // ---------- final states (own (U,R) values, all in registers) ----------
  {
    float* o = dout + (size_t)NB * NS * NZ;
    o[(size_t)R * NH + U] = h1last;
    o[(size_t)NB * NH + (size_t)R * NH + U] = c1reg;
    o[2 * (size_t)NB * NH + (size_t)R * NH + U] = h2last;
    o[3 * (size_t)NB * NH + (size_t)R * NH + U] = c2reg;
  }
}

extern "C" void kernel_launch(void* const* d_in, const int* in_sizes, int n_in,
                              void* d_out, int out_size, void* d_ws, size_t ws_size,
                              hipStream_t stream) {
  const float* z    = (const float*)d_in[0];
  const float* pg0  = (const float*)d_in[1];
  const float* h1   = (const float*)d_in[2];
  const float* c1   = (const float*)d_in[3];
  const float* h2   = (const float*)d_in[4];
  const float* c2   = (const float*)d_in[5];
  const float* W1   = (const float*)d_in[6];
  const float* b1   = (const float*)d_in[7];
  const float* Wih1 = (const float*)d_in[8];
  const float* Whh1 = (const float*)d_in[9];
  const float* bih1 = (const float*)d_in[10];
  const float* bhh1 = (const float*)d_in[11];
  const float* Wih2 = (const float*)d_in[12];
  const float* Whh2 = (const float*)d_in[13];
  const float* bih2 = (const float*)d_in[14];
  const float* bhh2 = (const float*)d_in[15];
  const float* W2   = (const float*)d_in[16];
  const float* b2   = (const float*)d_in[17];
  char* ws = (char*)d_ws;
  float* out = (float*)d_out;

  hipLaunchKernelGGL(init_state, dim3(256), dim3(256), 0, stream,
                     h1, h2, pg0, W1, b1, b2, ws);
  hipLaunchKernelGGL(prep_wfused, dim3(4096), dim3(256), 0, stream, W1, W2, ws);
  hipLaunchKernelGGL(gen_persistent, dim3(NWG), dim3(NT), LDS_BYTES, stream,
                     z, W1, b1, Wih1, Whh1, bih1, bhh1, Wih2, Whh2, bih2, bhh2, W2, b2,
                     c1, c2, out, ws);
}

// Round 5
// 25527.625 us; speedup vs baseline: 2.6510x; 1.6180x over previous
//
#include <hip/hip_runtime.h>

#define NB 64
#define NS 512
#define NZ 256
#define NH 1024
#define NWG 256
#define NT 256

typedef _Float16 f16;
typedef __attribute__((ext_vector_type(8))) _Float16 half8;
typedef __attribute__((ext_vector_type(4))) float f32x4;

// ---------------- ws layout (bytes) ----------------
#define WS_OUTP  0          // f16 [128][64][8]  relu output, packed A-frag layout
#define WS_H1P   131072     // f16 [2][128][64][8]
#define WS_H2P   393216     // f16 [2][128][64][8]
#define WS_BAR   655360     // barrier: L1[16] @+g*128, root @+2048, flag[8] @+4096+i*128
#define WS_WF    1179648    // f16 [1024][1024]  Wfused = W1p @ W2
#define WS_B1P   3276800    // f32 [1024]        b1 + W1p@b2
#define WS_PG0   3280896    // f16 [32][64][8]   packed prev_gen0
// ---------------- LDS layout (bytes) ----------------
#define L_W0   0            // 4 rows x 2576  ([W1z 256h | Wfused 1024h] + 16B pad)
#define L_W2   10304        // 1 row  x 2064  (W2[w] 1024h + pad)
#define L_W1   12368        // 16 rows x 4112 ([Wih1 1024h | Whh1 1024h] + pad)
#define L_WP2  78160        // 16 rows x 4112
#define L_W1P  143952       // 4 rows x 528   (W1p 256h + pad) for t==0
#define L_X    146064       // 4 waves x 1024B exchange scratch
#define LDS_BYTES 150160

__device__ __forceinline__ float sigf(float x) { return 1.f / (1.f + __expf(-x)); }
__device__ __forceinline__ float tanhfast(float x) { return 2.f / (1.f + __expf(-2.f * x)) - 1.f; }

__device__ __forceinline__ f32x4 MF(half8 a, half8 b, f32x4 c) {
  return __builtin_amdgcn_mfma_f32_16x16x32_f16(a, b, c, 0, 0, 0);
}

// -------- hierarchical tree barrier, RELAXED atomics + one fence per side --------
// Arrival: all waves drain stores (vmcnt), one release fence (single L2 writeback),
// then relaxed L1[w>>4] fetch_add; 16th arriver forwards to root; root's 16th
// publishes epoch to 8 flag replicas. Counters monotonic (no reset).
__device__ __forceinline__ void bar_arrive(char* bar, int w) {
  asm volatile("s_waitcnt vmcnt(0)" ::: "memory");   // this wave's stores complete
  __syncthreads();                                   // => all waves' stores complete
  if (threadIdx.x == 0) {
    __builtin_amdgcn_fence(__ATOMIC_RELEASE, "agent");  // one L2 writeback
    unsigned* l1 = (unsigned*)(bar + (size_t)(w >> 4) * 128);
    unsigned p1 = __hip_atomic_fetch_add(l1, 1u, __ATOMIC_RELAXED, __HIP_MEMORY_SCOPE_AGENT);
    if (((p1 + 1u) & 15u) == 0u) {      // group of 16 complete for this epoch
      unsigned* root = (unsigned*)(bar + 2048);
      unsigned p2 = __hip_atomic_fetch_add(root, 1u, __ATOMIC_RELAXED, __HIP_MEMORY_SCOPE_AGENT);
      if (((p2 + 1u) & 15u) == 0u) {    // all 16 groups forwarded -> epoch done
        unsigned e = (p2 + 1u) >> 4;
        #pragma unroll
        for (int i = 0; i < 8; ++i)
          __hip_atomic_store((unsigned*)(bar + 4096 + i * 128), e,
                             __ATOMIC_RELAXED, __HIP_MEMORY_SCOPE_AGENT);
      }
    }
  }
}
// Wait: relaxed poll of one replica line (no per-iteration invalidate), then ONE
// acquire fence so subsequent plain loads see the just-published phase data.
__device__ __forceinline__ void bar_wait(char* bar, int w, unsigned e) {
  if (threadIdx.x == 0) {
    unsigned* f = (unsigned*)(bar + 4096 + (size_t)(w & 7) * 128);  // 32 WGs per replica
    while (__hip_atomic_load(f, __ATOMIC_RELAXED, __HIP_MEMORY_SCOPE_AGENT) < e)
      __builtin_amdgcn_s_sleep(1);
    __builtin_amdgcn_fence(__ATOMIC_ACQUIRE, "agent");  // one invalidate
  }
  __syncthreads();
}

__global__ void init_state(const float* __restrict__ h1, const float* __restrict__ h2,
                           const float* __restrict__ pg0, const float* __restrict__ W1,
                           const float* __restrict__ b1, const float* __restrict__ b2,
                           char* __restrict__ ws) {
  int i = blockIdx.x * blockDim.x + threadIdx.x;  // 0..65535
  int R = i & 63;
  int U = i >> 6;
  f16* H1p = (f16*)(ws + WS_H1P);
  f16* H2p = (f16*)(ws + WS_H2P);
  int pidx = ((U >> 3) * 64 + R) * 8 + (U & 7);
  H1p[pidx] = (f16)h1[(size_t)R * NH + U];   // parity-0 buffer
  H2p[pidx] = (f16)h2[(size_t)R * NH + U];
  if (i < 16384) {  // pack prev_gen0: u in 0..255
    int u = i >> 6, r2 = i & 63;
    ((f16*)(ws + WS_PG0))[((u >> 3) * 64 + r2) * 8 + (u & 7)] = (f16)pg0[(size_t)r2 * NZ + u];
  }
  if (i < NH) {  // b1p = b1 + W1p @ b2
    float acc = b1[i];
    const float* wp = W1 + (size_t)i * (2 * NZ) + NZ;
    for (int mm = 0; mm < NZ; ++mm) acc = fmaf(wp[mm], b2[mm], acc);
    ((float*)(ws + WS_B1P))[i] = acc;
  }
  if (i < 8192) ((unsigned*)(ws + WS_BAR))[i] = 0u;  // counters + flags
}

__global__ void prep_wfused(const float* __restrict__ W1, const float* __restrict__ W2,
                            char* __restrict__ ws) {
  int u = blockIdx.x >> 2;
  int j = ((blockIdx.x & 3) << 8) + threadIdx.x;
  const float* wp = W1 + (size_t)u * (2 * NZ) + NZ;
  float acc = 0.f;
  for (int mm = 0; mm < NZ; ++mm) acc = fmaf(wp[mm], W2[(size_t)mm * NH + j], acc);
  ((f16*)(ws + WS_WF))[(size_t)u * NH + j] = (f16)acc;
}

__global__ __launch_bounds__(NT, 1) void gen_persistent(
    const float* __restrict__ z,
    const float* __restrict__ W1, const float* __restrict__ b1,
    const float* __restrict__ Wih1, const float* __restrict__ Whh1,
    const float* __restrict__ bih1, const float* __restrict__ bhh1,
    const float* __restrict__ Wih2, const float* __restrict__ Whh2,
    const float* __restrict__ bih2, const float* __restrict__ bhh2,
    const float* __restrict__ W2, const float* __restrict__ b2,
    const float* __restrict__ c1in, const float* __restrict__ c2in,
    float* __restrict__ dout, char* __restrict__ ws)
{
  extern __shared__ char smem[];
  const int w = blockIdx.x;
  const int tid = threadIdx.x;
  const int m = tid >> 6;      // wave -> batch rows 16m..16m+15
  const int l = tid & 63;
  const int c = l & 15;        // MFMA col / A-row-within-16
  const int kg = l >> 4;       // k-group

  f16* OutP = (f16*)(ws + WS_OUTP);
  f16* H1p = (f16*)(ws + WS_H1P);
  f16* H2p = (f16*)(ws + WS_H2P);
  const f16* Wf = (const f16*)(ws + WS_WF);
  const f16* Pg0p = (const f16*)(ws + WS_PG0);
  const float* b1p = (const float*)(ws + WS_B1P);
  char* bar = ws + WS_BAR;

  // ---- load this CU's weight slices into LDS (fp32 -> fp16), once ----
  for (int i = 0; i < 16; ++i) {
    int gi = i >> 2, uu = 4 * w + (i & 3);
    const float* s1i = Wih1 + (size_t)(gi * NH + uu) * NH;
    const float* s1h = Whh1 + (size_t)(gi * NH + uu) * NH;
    const float* s2i = Wih2 + (size_t)(gi * NH + uu) * NH;
    const float* s2h = Whh2 + (size_t)(gi * NH + uu) * NH;
    f16* d1 = (f16*)(smem + L_W1 + i * 4112);
    f16* d2 = (f16*)(smem + L_WP2 + i * 4112);
    for (int k = tid; k < NH; k += NT) {
      d1[k] = (f16)s1i[k]; d1[NH + k] = (f16)s1h[k];
      d2[k] = (f16)s2i[k]; d2[NH + k] = (f16)s2h[k];
    }
  }
  for (int i = 0; i < 4; ++i) {
    int uu = 4 * w + i;
    f16* d0 = (f16*)(smem + L_W0 + i * 2576);
    d0[tid] = (f16)W1[(size_t)uu * (2 * NZ) + tid];           // z part (256 = NT)
    for (int k = tid; k < NH; k += NT) d0[NZ + k] = Wf[(size_t)uu * NH + k];
    f16* dp = (f16*)(smem + L_W1P + i * 528);
    dp[tid] = (f16)W1[(size_t)uu * (2 * NZ) + NZ + tid];      // W1p part for t==0
  }
  {
    f16* dw2 = (f16*)(smem + L_W2);
    for (int k = tid; k < NH; k += NT) dw2[k] = (f16)W2[(size_t)w * NH + k];
  }
  __syncthreads();

  const int R = 16 * m + c;          // batch row
  const int U = 4 * w + kg;          // owned unit
  const int hpack = ((U >> 3) * 64 + R) * 8 + (U & 7);
  const float b0fused = b1p[U];
  const float b0plain = b1[U];
  const float bi1 = bih1[U] + bhh1[U];
  const float bf1 = bih1[NH + U] + bhh1[NH + U];
  const float bg1 = bih1[2 * NH + U] + bhh1[2 * NH + U];
  const float bo1 = bih1[3 * NH + U] + bhh1[3 * NH + U];
  const float bi2 = bih2[U] + bhh2[U];
  const float bf2 = bih2[NH + U] + bhh2[NH + U];
  const float bg2 = bih2[2 * NH + U] + bhh2[2 * NH + U];
  const float bo2 = bih2[3 * NH + U] + bhh2[3 * NH + U];
  const float b2w = b2[w];

  // cell states live in registers: this thread is the only reader/writer of (U,R)
  float c1reg = c1in[(size_t)R * NH + U];
  float c2reg = c2in[(size_t)R * NH + U];
  float h1last = 0.f, h2last = 0.f;

  float* scr = (float*)(smem + L_X) + m * 256;
  const char* brow0 = smem + L_W0 + (c & 3) * 2576 + kg * 16;
  const char* brow2 = smem + L_W2 + kg * 16;
  const char* brow1 = smem + L_W1 + c * 4112 + kg * 16;
  const char* browp2 = smem + L_WP2 + c * 4112 + kg * 16;
  const char* browp0 = smem + L_W1P + (c & 3) * 528 + kg * 16;
  const float* zlane = z + (size_t)R * NS * NZ + kg * 8;

  for (int t = 0; t < NS; ++t) {
    const int par = t & 1;
    const f16* h2prev = H2p + par * 65536;
    const f16* h1prev = H1p + par * 65536;
    const unsigned eb = 3u * (unsigned)t;

    // ================= P0 =================
    // ---- ind0: z-part (+ pg0 path at t==0) — does not need the barrier ----
    f32x4 ao0 = {0.f, 0.f, 0.f, 0.f}, ao1 = ao0, ap0 = ao0, ap1 = ao0;
    {
      const float* zt = zlane + (size_t)t * NZ;
      #pragma unroll
      for (int kk = 0; kk < 8; ++kk) {
        f32x4 f0 = *(const f32x4*)(zt + kk * 32);
        f32x4 f1 = *(const f32x4*)(zt + kk * 32 + 4);
        half8 a;
        a[0] = (f16)f0[0]; a[1] = (f16)f0[1]; a[2] = (f16)f0[2]; a[3] = (f16)f0[3];
        a[4] = (f16)f1[0]; a[5] = (f16)f1[1]; a[6] = (f16)f1[2]; a[7] = (f16)f1[3];
        half8 b = *(const half8*)(brow0 + kk * 64);
        if (kk & 1) ao1 = MF(a, b, ao1); else ao0 = MF(a, b, ao0);
      }
      if (t == 0) {
        #pragma unroll
        for (int kk = 0; kk < 8; ++kk) {
          half8 a = *(const half8*)(Pg0p + (((4 * kk + kg) * 64 + R) << 3));
          half8 b = *(const half8*)(browp0 + kk * 64);
          if (kk & 1) ao1 = MF(a, b, ao1); else ao0 = MF(a, b, ao0);
        }
      }
    }
    // ---- wait for h2prev (epoch 3t = P2 of step t-1) ----
    bar_wait(bar, w, eb);
    // ---- dep0: h2prev @ [Wfused | W2] ----
    if (t > 0) {
      #pragma unroll 8
      for (int kk = 0; kk < 32; ++kk) {
        half8 a = *(const half8*)(h2prev + (((4 * kk + kg) * 64 + R) << 3));
        half8 bwf = *(const half8*)(brow0 + 512 + kk * 64);
        half8 bw2 = *(const half8*)(brow2 + kk * 64);
        if (kk & 1) { ao1 = MF(a, bwf, ao1); ap1 = MF(a, bw2, ap1); }
        else        { ao0 = MF(a, bwf, ao0); ap0 = MF(a, bw2, ap0); }
      }
    }
    {
      f32x4 D = ao0 + ao1;
      if (c < 4) {
        #pragma unroll
        for (int v = 0; v < 4; ++v) scr[c * 16 + kg * 4 + v] = D[v];
      }
      float pre = scr[kg * 16 + c] + ((t == 0) ? b0plain : b0fused);
      OutP[hpack] = (f16)fmaxf(pre, 0.f);
    }
    bar_arrive(bar, w);   // completes epoch 3t+1
    // deferred lazy pg(t-1) store — pure output, overlapped with others' waits
    if (t > 0 && c == 0) {
      f32x4 Dp = ap0 + ap1;
      #pragma unroll
      for (int v = 0; v < 4; ++v) {
        int Rp = 16 * m + kg * 4 + v;
        dout[((size_t)Rp * NS + (t - 1)) * NZ + w] = Dp[v] + b2w;
      }
    }

    // ================= P1 =================
    f32x4 g0 = {0.f, 0.f, 0.f, 0.f}, g1 = g0;
    // ---- ind1: h1prev @ Whh1 (one step old — already visible) ----
    #pragma unroll 8
    for (int kk = 0; kk < 32; ++kk) {
      half8 a = *(const half8*)(h1prev + (((4 * kk + kg) * 64 + R) << 3));
      half8 b = *(const half8*)(brow1 + 2048 + kk * 64);
      if (kk & 1) g1 = MF(a, b, g1); else g0 = MF(a, b, g0);
    }
    bar_wait(bar, w, eb + 1);
    // ---- dep1: out @ Wih1 ----
    #pragma unroll 8
    for (int kk = 0; kk < 32; ++kk) {
      half8 a = *(const half8*)(OutP + (((4 * kk + kg) * 64 + R) << 3));
      half8 b = *(const half8*)(brow1 + kk * 64);
      if (kk & 1) g1 = MF(a, b, g1); else g0 = MF(a, b, g0);
    }
    {
      f32x4 D = g0 + g1;
      #pragma unroll
      for (int v = 0; v < 4; ++v) scr[c * 16 + kg * 4 + v] = D[v];
      float ai = scr[kg * 16 + c];
      float af = scr[(4 + kg) * 16 + c];
      float ag = scr[(8 + kg) * 16 + c];
      float aoo = scr[(12 + kg) * 16 + c];
      float iv = sigf(ai + bi1), fv = sigf(af + bf1);
      float gv = tanhfast(ag + bg1), ov = sigf(aoo + bo1);
      float cn = fmaf(fv, c1reg, iv * gv);
      c1reg = cn;
      float hv = ov * tanhfast(cn);
      h1last = hv;
      H1p[(par ^ 1) * 65536 + hpack] = (f16)hv;
    }
    bar_arrive(bar, w);   // completes epoch 3t+2

    // ================= P2 =================
    f32x4 q0 = {0.f, 0.f, 0.f, 0.f}, q1 = q0;
    // ---- ind2: h2prev @ Whh2 ----
    #pragma unroll 8
    for (int kk = 0; kk < 32; ++kk) {
      half8 a = *(const half8*)(h2prev + (((4 * kk + kg) * 64 + R) << 3));
      half8 b = *(const half8*)(browp2 + 2048 + kk * 64);
      if (kk & 1) q1 = MF(a, b, q1); else q0 = MF(a, b, q0);
    }
    bar_wait(bar, w, eb + 2);
    // ---- dep2: h1new @ Wih2 ----
    {
      const f16* h1new = H1p + (par ^ 1) * 65536;
      #pragma unroll 8
      for (int kk = 0; kk < 32; ++kk) {
        half8 a = *(const half8*)(h1new + (((4 * kk + kg) * 64 + R) << 3));
        half8 b = *(const half8*)(browp2 + kk * 64);
        if (kk & 1) q1 = MF(a, b, q1); else q0 = MF(a, b, q0);
      }
    }
    {
      f32x4 D = q0 + q1;
      #pragma unroll
      for (int v = 0; v < 4; ++v) scr[c * 16 + kg * 4 + v] = D[v];
      float ai = scr[kg * 16 + c];
      float af = scr[(4 + kg) * 16 + c];
      float ag = scr[(8 + kg) * 16 + c];
      float aoo = scr[(12 + kg) * 16 + c];
      float iv = sigf(ai + bi2), fv = sigf(af + bf2);
      float gv = tanhfast(ag + bg2), ov = sigf(aoo + bo2);
      float cn = fmaf(fv, c2reg, iv * gv);
      c2reg = cn;
      float hv = ov * tanhfast(cn);
      h2last = hv;
      H2p[(par ^ 1) * 65536 + hpack] = (f16)hv;
    }
    bar_arrive(bar, w);   // completes epoch 3t+3
  }

  // ---------- tail: pg for t=511 from final h2 (parity 0) ----------
  bar_wait(bar, w, 3u * NS);
  {
    f32x4 ap0 = {0.f, 0.f, 0.f, 0.f}, ap1 = ap0;
    #pragma unroll 8
    for (int kk = 0; kk < 32; ++kk) {
      half8 a = *(const half8*)(H2p + (((4 * kk + kg) * 64 + R) << 3));
      half8 b = *(const half8*)(brow2 + kk * 64);
      if (kk & 1) ap1 = MF(a, b, ap1); else ap0 = MF(a, b, ap0);
    }
    if (c == 0) {
      f32x4 Dp = ap0 + ap1;
      #pragma unroll
      for (int v = 0; v < 4; ++v) {
        int Rp = 16 * m + kg * 4 + v;
        dout[((size_t)Rp * NS + (NS - 1)) * NZ + w] = Dp[v] + b2w;
      }
    }
  }

  // ---------- final states (own (U,R) values, all in registers) ----------
  {
    float* o = dout + (size_t)NB * NS * NZ;
    o[(size_t)R * NH + U] = h1last;
    o[(size_t)NB * NH + (size_t)R * NH + U] = c1reg;
    o[2 * (size_t)NB * NH + (size_t)R * NH + U] = h2last;
    o[3 * (size_t)NB * NH + (size_t)R * NH + U] = c2reg;
  }
}

extern "C" void kernel_launch(void* const* d_in, const int* in_sizes, int n_in,
                              void* d_out, int out_size, void* d_ws, size_t ws_size,
                              hipStream_t stream) {
  const float* z    = (const float*)d_in[0];
  const float* pg0  = (const float*)d_in[1];
  const float* h1   = (const float*)d_in[2];
  const float* c1   = (const float*)d_in[3];
  const float* h2   = (const float*)d_in[4];
  const float* c2   = (const float*)d_in[5];
  const float* W1   = (const float*)d_in[6];
  const float* b1   = (const float*)d_in[7];
  const float* Wih1 = (const float*)d_in[8];
  const float* Whh1 = (const float*)d_in[9];
  const float* bih1 = (const float*)d_in[10];
  const float* bhh1 = (const float*)d_in[11];
  const float* Wih2 = (const float*)d_in[12];
  const float* Whh2 = (const float*)d_in[13];
  const float* bih2 = (const float*)d_in[14];
  const float* bhh2 = (const float*)d_in[15];
  const float* W2   = (const float*)d_in[16];
  const float* b2   = (const float*)d_in[17];
  char* ws = (char*)d_ws;
  float* out = (float*)d_out;

  hipLaunchKernelGGL(init_state, dim3(256), dim3(256), 0, stream,
                     h1, h2, pg0, W1, b1, b2, ws);
  hipLaunchKernelGGL(prep_wfused, dim3(4096), dim3(256), 0, stream, W1, W2, ws);
  hipLaunchKernelGGL(gen_persistent, dim3(NWG), dim3(NT), LDS_BYTES, stream,
                     z, W1, b1, Wih1, Whh1, bih1, bhh1, Wih2, Whh2, bih2, bhh2, W2, b2,
                     c1, c2, out, ws);
}

// Round 6
// 11412.077 us; speedup vs baseline: 5.9301x; 2.2369x over previous
//
#include <hip/hip_runtime.h>

#define NB 64
#define NS 512
#define NZ 256
#define NH 1024
#define NWG 256
#define NT 512

typedef _Float16 f16;
typedef __attribute__((ext_vector_type(8))) _Float16 half8;
typedef __attribute__((ext_vector_type(4))) float f32x4;

// ---------------- ws layout (bytes) ----------------
#define WS_OUTP  0          // f16 [128][64][8]  relu output, packed A-frag layout
#define WS_H1P   131072     // f16 [2][128][64][8]
#define WS_H2P   393216     // f16 [2][128][64][8]
#define WS_BAR   655360     // barrier: L1[16] @+g*128, root @+2048, flag[8] @+4096+i*128
#define WS_WF    1179648    // f16 [1024][1024]  Wfused = W1p @ W2
#define WS_B1P   3276800    // f32 [1024]        b1 + W1p@b2
#define WS_PG0   3280896    // f16 [32][64][8]   packed prev_gen0
// ---------------- LDS layout (bytes) ----------------
#define L_W0   0            // 4 rows x 2576  ([W1z 256h | Wfused 1024h] + 16B pad)
#define L_W2   10304        // 1 row  x 2064  (W2[w] 1024h + pad)
#define L_W1   12368        // 16 rows x 4112 ([Wih1 1024h | Whh1 1024h] + pad)
#define L_WP2  78160        // 16 rows x 4112
#define L_W1P  143952       // 4 rows x 528   (W1p 256h + pad) for t==0
#define L_X    146064       // 4 kh1-waves x 1024B gate-exchange scratch
#define L_X2   150160       // 4KB  K-split partial exchange (f32[4][256])
#define L_X3   154256       // 256B pg partial exchange (f32[4][16])
#define LDS_BYTES 154512

__device__ __forceinline__ float sigf(float x) { return 1.f / (1.f + __expf(-x)); }
__device__ __forceinline__ float tanhfast(float x) { return 2.f / (1.f + __expf(-2.f * x)) - 1.f; }

__device__ __forceinline__ f32x4 MF(half8 a, half8 b, f32x4 c) {
  return __builtin_amdgcn_mfma_f32_16x16x32_f16(a, b, c, 0, 0, 0);
}

// Coherent (LLC-level) 16B load as 2x8B relaxed agent atomics — bypasses L2,
// so no acquire fences / cache invalidates are ever needed.
__device__ __forceinline__ half8 ald16(const f16* p) {
  unsigned long long* q = (unsigned long long*)p;
  union { unsigned long long u[2]; half8 h; } x;
  x.u[0] = __hip_atomic_load(q, __ATOMIC_RELAXED, __HIP_MEMORY_SCOPE_AGENT);
  x.u[1] = __hip_atomic_load(q + 1, __ATOMIC_RELAXED, __HIP_MEMORY_SCOPE_AGENT);
  return x.h;
}
// Coherent 2B activation store (write-through to LLC, no dirty L2 lines).
__device__ __forceinline__ void ast2(f16* p, f16 v) {
  unsigned short b;
  __builtin_memcpy(&b, &v, 2);
  __hip_atomic_store((unsigned short*)p, b, __ATOMIC_RELAXED, __HIP_MEMORY_SCOPE_AGENT);
}
__device__ __forceinline__ void ast4f(float* p, float v) {
  __hip_atomic_store((unsigned*)p, __float_as_uint(v), __ATOMIC_RELAXED, __HIP_MEMORY_SCOPE_AGENT);
}

// -------- fence-free tree barrier --------
// Release pattern: every wave drains its (write-through) stores, syncthreads,
// then tid0 does relaxed tree RMWs. Wait: relaxed poll + control dependence.
__device__ __forceinline__ void bar_arrive(char* bar, int w) {
  asm volatile("s_waitcnt vmcnt(0)" ::: "memory");   // stores visible at LLC
  __syncthreads();
  if (threadIdx.x == 0) {
    unsigned* l1 = (unsigned*)(bar + (size_t)(w >> 4) * 128);
    unsigned p1 = __hip_atomic_fetch_add(l1, 1u, __ATOMIC_RELAXED, __HIP_MEMORY_SCOPE_AGENT);
    if (((p1 + 1u) & 15u) == 0u) {
      unsigned* root = (unsigned*)(bar + 2048);
      unsigned p2 = __hip_atomic_fetch_add(root, 1u, __ATOMIC_RELAXED, __HIP_MEMORY_SCOPE_AGENT);
      if (((p2 + 1u) & 15u) == 0u) {
        unsigned e = (p2 + 1u) >> 4;
        #pragma unroll
        for (int i = 0; i < 8; ++i)
          __hip_atomic_store((unsigned*)(bar + 4096 + i * 128), e,
                             __ATOMIC_RELAXED, __HIP_MEMORY_SCOPE_AGENT);
      }
    }
  }
}
__device__ __forceinline__ void bar_wait(char* bar, int w, unsigned e) {
  if (threadIdx.x == 0) {
    unsigned* f = (unsigned*)(bar + 4096 + (size_t)(w & 7) * 128);
    while (__hip_atomic_load(f, __ATOMIC_RELAXED, __HIP_MEMORY_SCOPE_AGENT) < e)
      __builtin_amdgcn_s_sleep(1);
    asm volatile("" ::: "memory");     // compiler barrier; HW order via control dep
  }
  __syncthreads();
}

__global__ void init_state(const float* __restrict__ h1, const float* __restrict__ h2,
                           const float* __restrict__ pg0, const float* __restrict__ W1,
                           const float* __restrict__ b1, const float* __restrict__ b2,
                           char* __restrict__ ws) {
  int i = blockIdx.x * blockDim.x + threadIdx.x;  // 0..65535
  int R = i & 63;
  int U = i >> 6;
  f16* H1p = (f16*)(ws + WS_H1P);
  f16* H2p = (f16*)(ws + WS_H2P);
  int pidx = ((U >> 3) * 64 + R) * 8 + (U & 7);
  H1p[pidx] = (f16)h1[(size_t)R * NH + U];   // parity-0 buffer
  H2p[pidx] = (f16)h2[(size_t)R * NH + U];
  if (i < 16384) {
    int u = i >> 6, r2 = i & 63;
    ((f16*)(ws + WS_PG0))[((u >> 3) * 64 + r2) * 8 + (u & 7)] = (f16)pg0[(size_t)r2 * NZ + u];
  }
  if (i < NH) {  // b1p = b1 + W1p @ b2
    float acc = b1[i];
    const float* wp = W1 + (size_t)i * (2 * NZ) + NZ;
    for (int mm = 0; mm < NZ; ++mm) acc = fmaf(wp[mm], b2[mm], acc);
    ((float*)(ws + WS_B1P))[i] = acc;
  }
  if (i < 8192) ((unsigned*)(ws + WS_BAR))[i] = 0u;
}

__global__ void prep_wfused(const float* __restrict__ W1, const float* __restrict__ W2,
                            char* __restrict__ ws) {
  int u = blockIdx.x >> 2;
  int j = ((blockIdx.x & 3) << 8) + threadIdx.x;
  const float* wp = W1 + (size_t)u * (2 * NZ) + NZ;
  float acc = 0.f;
  for (int mm = 0; mm < NZ; ++mm) acc = fmaf(wp[mm], W2[(size_t)mm * NH + j], acc);
  ((f16*)(ws + WS_WF))[(size_t)u * NH + j] = (f16)acc;
}

__global__ __launch_bounds__(NT, 1) void gen_persistent(
    const float* __restrict__ z,
    const float* __restrict__ W1, const float* __restrict__ b1,
    const float* __restrict__ Wih1, const float* __restrict__ Whh1,
    const float* __restrict__ bih1, const float* __restrict__ bhh1,
    const float* __restrict__ Wih2, const float* __restrict__ Whh2,
    const float* __restrict__ bih2, const float* __restrict__ bhh2,
    const float* __restrict__ W2, const float* __restrict__ b2,
    const float* __restrict__ c1in, const float* __restrict__ c2in,
    float* __restrict__ dout, char* __restrict__ ws)
{
  extern __shared__ char smem[];
  const int w = blockIdx.x;
  const int tid = threadIdx.x;
  const int w8 = tid >> 6;     // wave 0..7
  const int m = w8 & 3;        // batch-row block (rows 16m..16m+15)
  const int kh = w8 >> 2;      // K half: 0 = low, 1 = high
  const int l = tid & 63;
  const int c = l & 15;
  const int kg = l >> 4;

  f16* OutP = (f16*)(ws + WS_OUTP);
  f16* H1p = (f16*)(ws + WS_H1P);
  f16* H2p = (f16*)(ws + WS_H2P);
  const f16* Wf = (const f16*)(ws + WS_WF);
  const f16* Pg0p = (const f16*)(ws + WS_PG0);
  const float* b1p = (const float*)(ws + WS_B1P);
  char* bar = ws + WS_BAR;

  // ---- load this CU's weight slices into LDS (fp32 -> fp16), once ----
  for (int i = 0; i < 16; ++i) {
    int gi = i >> 2, uu = 4 * w + (i & 3);
    const float* s1i = Wih1 + (size_t)(gi * NH + uu) * NH;
    const float* s1h = Whh1 + (size_t)(gi * NH + uu) * NH;
    const float* s2i = Wih2 + (size_t)(gi * NH + uu) * NH;
    const float* s2h = Whh2 + (size_t)(gi * NH + uu) * NH;
    f16* d1 = (f16*)(smem + L_W1 + i * 4112);
    f16* d2 = (f16*)(smem + L_WP2 + i * 4112);
    for (int k = tid; k < NH; k += NT) {
      d1[k] = (f16)s1i[k]; d1[NH + k] = (f16)s1h[k];
      d2[k] = (f16)s2i[k]; d2[NH + k] = (f16)s2h[k];
    }
  }
  for (int i = 0; i < 4; ++i) {
    int uu = 4 * w + i;
    f16* d0 = (f16*)(smem + L_W0 + i * 2576);
    if (tid < 256) d0[tid] = (f16)W1[(size_t)uu * (2 * NZ) + tid];   // z part
    for (int k = tid; k < NH; k += NT) d0[NZ + k] = Wf[(size_t)uu * NH + k];
    f16* dp = (f16*)(smem + L_W1P + i * 528);
    if (tid < 256) dp[tid] = (f16)W1[(size_t)uu * (2 * NZ) + NZ + tid];  // W1p for t==0
  }
  {
    f16* dw2 = (f16*)(smem + L_W2);
    for (int k = tid; k < NH; k += NT) dw2[k] = (f16)W2[(size_t)w * NH + k];
  }
  __syncthreads();

  const int R = 16 * m + c;          // batch row
  const int U = 4 * w + kg;          // owned unit (kh==1 threads do gate math)
  const int hpack = ((U >> 3) * 64 + R) * 8 + (U & 7);
  const float b0fused = b1p[U];
  const float b0plain = b1[U];
  const float bi1 = bih1[U] + bhh1[U];
  const float bf1 = bih1[NH + U] + bhh1[NH + U];
  const float bg1 = bih1[2 * NH + U] + bhh1[2 * NH + U];
  const float bo1 = bih1[3 * NH + U] + bhh1[3 * NH + U];
  const float bi2 = bih2[U] + bhh2[U];
  const float bf2 = bih2[NH + U] + bhh2[NH + U];
  const float bg2 = bih2[2 * NH + U] + bhh2[2 * NH + U];
  const float bo2 = bih2[3 * NH + U] + bhh2[3 * NH + U];
  const float b2w = b2[w];

  float c1reg = c1in[(size_t)R * NH + U];
  float c2reg = c2in[(size_t)R * NH + U];
  float h1last = 0.f, h2last = 0.f;

  float* scr  = (float*)(smem + L_X) + m * 256;       // kh1 intra-wave gate exchange
  float* scr2 = (float*)(smem + L_X2) + m * 256;      // K-split partial (per row-block)
  float* scr3 = (float*)(smem + L_X3) + m * 16;       // pg partial
  const char* brow0 = smem + L_W0 + (c & 3) * 2576 + kg * 16;
  const char* brow2 = smem + L_W2 + kg * 16;
  const char* brow1 = smem + L_W1 + c * 4112 + kg * 16;
  const char* browp2 = smem + L_WP2 + c * 4112 + kg * 16;
  const char* browp0 = smem + L_W1P + (c & 3) * 528 + kg * 16;
  const float* zlane = z + (size_t)R * NS * NZ + kg * 8;

  for (int t = 0; t < NS; ++t) {
    const int par = t & 1;
    f16* h2prev = H2p + par * 65536;
    f16* h1prev = H1p + par * 65536;
    const unsigned eb = 3u * (unsigned)t;

    // ================= P0 =================
    f32x4 ao0 = {0.f, 0.f, 0.f, 0.f}, ao1 = ao0, ap0 = ao0, ap1 = ao0;
    if (t == 0) {
      if (kh == 0) {   // z part, all 8 chunks
        #pragma unroll
        for (int kk = 0; kk < 8; ++kk) {
          f32x4 f0 = *(const f32x4*)(zlane + kk * 32);
          f32x4 f1 = *(const f32x4*)(zlane + kk * 32 + 4);
          half8 a;
          a[0] = (f16)f0[0]; a[1] = (f16)f0[1]; a[2] = (f16)f0[2]; a[3] = (f16)f0[3];
          a[4] = (f16)f1[0]; a[5] = (f16)f1[1]; a[6] = (f16)f1[2]; a[7] = (f16)f1[3];
          half8 b = *(const half8*)(brow0 + kk * 64);
          if (kk & 1) ao1 = MF(a, b, ao1); else ao0 = MF(a, b, ao0);
        }
      } else {         // true prev_gen0 path through W1p
        #pragma unroll
        for (int kk = 0; kk < 8; ++kk) {
          half8 a = *(const half8*)(Pg0p + (((4 * kk + kg) * 64 + R) << 3));
          half8 b = *(const half8*)(browp0 + kk * 64);
          if (kk & 1) ao1 = MF(a, b, ao1); else ao0 = MF(a, b, ao0);
        }
      }
      bar_wait(bar, w, eb);
    } else {
      // ind0: z part, K split 4+4 chunks
      const float* zt = zlane + (size_t)t * NZ;
      #pragma unroll
      for (int i = 0; i < 4; ++i) {
        int kk = kh * 4 + i;
        f32x4 f0 = *(const f32x4*)(zt + kk * 32);
        f32x4 f1 = *(const f32x4*)(zt + kk * 32 + 4);
        half8 a;
        a[0] = (f16)f0[0]; a[1] = (f16)f0[1]; a[2] = (f16)f0[2]; a[3] = (f16)f0[3];
        a[4] = (f16)f1[0]; a[5] = (f16)f1[1]; a[6] = (f16)f1[2]; a[7] = (f16)f1[3];
        half8 b = *(const half8*)(brow0 + kk * 64);
        if (i & 1) ao1 = MF(a, b, ao1); else ao0 = MF(a, b, ao0);
      }
      bar_wait(bar, w, eb);
      // dep0: h2prev @ [Wfused | W2], K split 16+16
      #pragma unroll 8
      for (int i = 0; i < 16; ++i) {
        int kk = kh * 16 + i;
        half8 a = ald16(h2prev + (((4 * kk + kg) * 64 + R) << 3));
        half8 bwf = *(const half8*)(brow0 + 512 + kk * 64);
        half8 bw2 = *(const half8*)(brow2 + kk * 64);
        if (i & 1) { ao1 = MF(a, bwf, ao1); ap1 = MF(a, bw2, ap1); }
        else       { ao0 = MF(a, bwf, ao0); ap0 = MF(a, bw2, ap0); }
      }
    }
    {
      f32x4 D = ao0 + ao1;
      f32x4 Dp = ap0 + ap1;
      if (kh == 0) {
        if (c < 4) {
          #pragma unroll
          for (int v = 0; v < 4; ++v) scr2[c * 16 + kg * 4 + v] = D[v];
        }
        if (c == 0 && t > 0) {
          #pragma unroll
          for (int v = 0; v < 4; ++v) scr3[kg * 4 + v] = Dp[v];
        }
      }
      __syncthreads();
      if (kh == 1) {
        if (c < 4) {
          #pragma unroll
          for (int v = 0; v < 4; ++v) scr[c * 16 + kg * 4 + v] = D[v] + scr2[c * 16 + kg * 4 + v];
        }
        float pre = scr[kg * 16 + c] + ((t == 0) ? b0plain : b0fused);
        ast2(&OutP[hpack], (f16)fmaxf(pre, 0.f));
        if (t > 0 && c == 0) {
          #pragma unroll
          for (int v = 0; v < 4; ++v) {
            int Rp = 16 * m + kg * 4 + v;
            ast4f(&dout[((size_t)Rp * NS + (t - 1)) * NZ + w], Dp[v] + scr3[kg * 4 + v] + b2w);
          }
        }
      }
    }
    bar_arrive(bar, w);   // completes epoch 3t+1

    // ================= P1 =================
    f32x4 g0 = {0.f, 0.f, 0.f, 0.f}, g1 = g0;
    #pragma unroll 8
    for (int i = 0; i < 16; ++i) {   // ind1: h1prev @ Whh1 (one step old)
      int kk = kh * 16 + i;
      half8 a = ald16(h1prev + (((4 * kk + kg) * 64 + R) << 3));
      half8 b = *(const half8*)(brow1 + 2048 + kk * 64);
      if (i & 1) g1 = MF(a, b, g1); else g0 = MF(a, b, g0);
    }
    bar_wait(bar, w, eb + 1);
    #pragma unroll 8
    for (int i = 0; i < 16; ++i) {   // dep1: out @ Wih1
      int kk = kh * 16 + i;
      half8 a = ald16(OutP + (((4 * kk + kg) * 64 + R) << 3));
      half8 b = *(const half8*)(brow1 + kk * 64);
      if (i & 1) g1 = MF(a, b, g1); else g0 = MF(a, b, g0);
    }
    {
      f32x4 D = g0 + g1;
      if (kh == 0) {
        #pragma unroll
        for (int v = 0; v < 4; ++v) scr2[c * 16 + kg * 4 + v] = D[v];
      }
      __syncthreads();
      if (kh == 1) {
        #pragma unroll
        for (int v = 0; v < 4; ++v) scr[c * 16 + kg * 4 + v] = D[v] + scr2[c * 16 + kg * 4 + v];
        float ai = scr[kg * 16 + c];
        float af = scr[(4 + kg) * 16 + c];
        float ag = scr[(8 + kg) * 16 + c];
        float aoo = scr[(12 + kg) * 16 + c];
        float iv = sigf(ai + bi1), fv = sigf(af + bf1);
        float gv = tanhfast(ag + bg1), ov = sigf(aoo + bo1);
        float cn = fmaf(fv, c1reg, iv * gv);
        c1reg = cn;
        float hv = ov * tanhfast(cn);
        h1last = hv;
        ast2(&H1p[(par ^ 1) * 65536 + hpack], (f16)hv);
      }
    }
    bar_arrive(bar, w);   // completes epoch 3t+2

    // ================= P2 =================
    f32x4 q0 = {0.f, 0.f, 0.f, 0.f}, q1 = q0;
    #pragma unroll 8
    for (int i = 0; i < 16; ++i) {   // ind2: h2prev @ Whh2
      int kk = kh * 16 + i;
      half8 a = ald16(h2prev + (((4 * kk + kg) * 64 + R) << 3));
      half8 b = *(const half8*)(browp2 + 2048 + kk * 64);
      if (i & 1) q1 = MF(a, b, q1); else q0 = MF(a, b, q0);
    }
    bar_wait(bar, w, eb + 2);
    {
      f16* h1new = H1p + (par ^ 1) * 65536;
      #pragma unroll 8
      for (int i = 0; i < 16; ++i) {  // dep2: h1new @ Wih2
        int kk = kh * 16 + i;
        half8 a = ald16(h1new + (((4 * kk + kg) * 64 + R) << 3));
        half8 b = *(const half8*)(browp2 + kk * 64);
        if (i & 1) q1 = MF(a, b, q1); else q0 = MF(a, b, q0);
      }
    }
    {
      f32x4 D = q0 + q1;
      if (kh == 0) {
        #pragma unroll
        for (int v = 0; v < 4; ++v) scr2[c * 16 + kg * 4 + v] = D[v];
      }
      __syncthreads();
      if (kh == 1) {
        #pragma unroll
        for (int v = 0; v < 4; ++v) scr[c * 16 + kg * 4 + v] = D[v] + scr2[c * 16 + kg * 4 + v];
        float ai = scr[kg * 16 + c];
        float af = scr[(4 + kg) * 16 + c];
        float ag = scr[(8 + kg) * 16 + c];
        float aoo = scr[(12 + kg) * 16 + c];
        float iv = sigf(ai + bi2), fv = sigf(af + bf2);
        float gv = tanhfast(ag + bg2), ov = sigf(aoo + bo2);
        float cn = fmaf(fv, c2reg, iv * gv);
        c2reg = cn;
        float hv = ov * tanhfast(cn);
        h2last = hv;
        ast2(&H2p[(par ^ 1) * 65536 + hpack], (f16)hv);
      }
    }
    bar_arrive(bar, w);   // completes epoch 3t+3
  }

  // ---------- tail: pg for t=511 from final h2 (parity 0) ----------
  bar_wait(bar, w, 3u * NS);
  {
    f32x4 ap0t = {0.f, 0.f, 0.f, 0.f}, ap1t = ap0t;
    #pragma unroll 8
    for (int i = 0; i < 16; ++i) {
      int kk = kh * 16 + i;
      half8 a = ald16(H2p + (((4 * kk + kg) * 64 + R) << 3));
      half8 b = *(const half8*)(brow2 + kk * 64);
      if (i & 1) ap1t = MF(a, b, ap1t); else ap0t = MF(a, b, ap0t);
    }
    f32x4 Dp = ap0t + ap1t;
    if (kh == 0 && c == 0) {
      #pragma unroll
      for (int v = 0; v < 4; ++v) scr3[kg * 4 + v] = Dp[v];
    }
    __syncthreads();
    if (kh == 1 && c == 0) {
      #pragma unroll
      for (int v = 0; v < 4; ++v) {
        int Rp = 16 * m + kg * 4 + v;
        dout[((size_t)Rp * NS + (NS - 1)) * NZ + w] = Dp[v] + scr3[kg * 4 + v] + b2w;
      }
    }
  }

  // ---------- final states (kh1 threads own (U,R), all in registers) ----------
  if (kh == 1) {
    float* o = dout + (size_t)NB * NS * NZ;
    o[(size_t)R * NH + U] = h1last;
    o[(size_t)NB * NH + (size_t)R * NH + U] = c1reg;
    o[2 * (size_t)NB * NH + (size_t)R * NH + U] = h2last;
    o[3 * (size_t)NB * NH + (size_t)R * NH + U] = c2reg;
  }
}

extern "C" void kernel_launch(void* const* d_in, const int* in_sizes, int n_in,
                              void* d_out, int out_size, void* d_ws, size_t ws_size,
                              hipStream_t stream) {
  const float* z    = (const float*)d_in[0];
  const float* pg0  = (const float*)d_in[1];
  const float* h1   = (const float*)d_in[2];
  const float* c1   = (const float*)d_in[3];
  const float* h2   = (const float*)d_in[4];
  const float* c2   = (const float*)d_in[5];
  const float* W1   = (const float*)d_in[6];
  const float* b1   = (const float*)d_in[7];
  const float* Wih1 = (const float*)d_in[8];
  const float* Whh1 = (const float*)d_in[9];
  const float* bih1 = (const float*)d_in[10];
  const float* bhh1 = (const float*)d_in[11];
  const float* Wih2 = (const float*)d_in[12];
  const float* Whh2 = (const float*)d_in[13];
  const float* bih2 = (const float*)d_in[14];
  const float* bhh2 = (const float*)d_in[15];
  const float* W2   = (const float*)d_in[16];
  const float* b2   = (const float*)d_in[17];
  char* ws = (char*)d_ws;
  float* out = (float*)d_out;

  hipLaunchKernelGGL(init_state, dim3(256), dim3(256), 0, stream,
                     h1, h2, pg0, W1, b1, b2, ws);
  hipLaunchKernelGGL(prep_wfused, dim3(4096), dim3(256), 0, stream, W1, W2, ws);
  hipLaunchKernelGGL(gen_persistent, dim3(NWG), dim3(NT), LDS_BYTES, stream,
                     z, W1, b1, Wih1, Whh1, bih1, bhh1, Wih2, Whh2, bih2, bhh2, W2, b2,
                     c1, c2, out, ws);
}

// Round 7
// 11192.496 us; speedup vs baseline: 6.0464x; 1.0196x over previous
//
#include <hip/hip_runtime.h>

#define NB 64
#define NS 512
#define NZ 256
#define NH 1024
#define NWG 256
#define NT 512

typedef _Float16 f16;
typedef unsigned long long u64;
typedef __attribute__((ext_vector_type(8))) _Float16 half8;
typedef __attribute__((ext_vector_type(4))) float f32x4;

// ---------------- ws layout (bytes) ----------------
// Activations in PACKED4: element (u,R) at ((u>>2)*64 + R)*4 + (u&3)  [f16]
#define WS_OUTP  0          // f16 [256 ch][64][4]
#define WS_H1P   131072     // f16 [2][256 ch][64][4]
#define WS_H2P   393216     // f16 [2][256 ch][64][4]
#define WS_BAR   655360     // 16 counter lines, 128B apart
#define WS_WF    1179648    // f16 [1024][1024]  Wfused = W1p @ W2
#define WS_B1P   3276800    // f32 [1024]        b1 + W1p@b2
#define WS_PG0   3280896    // f16 [64 ch][64][4] packed prev_gen0
// ---------------- LDS layout (bytes) ----------------
#define L_W0   0            // 4 rows x 2576  ([W1z 256h | Wfused 1024h] + 16B pad)
#define L_W2   10304        // 1 row  x 2064  (W2[w] 1024h + pad)
#define L_W1   12368        // 16 rows x 4112 ([Wih1 1024h | Whh1 1024h] + pad)
#define L_WP2  78160        // 16 rows x 4112
#define L_W1P  143952       // 4 rows x 528   (W1p 256h + pad) for t==0
#define L_X    146064       // 4 kh1-waves x 1024B gate-exchange scratch
#define L_X2   150160       // 4KB  K-split partial exchange (f32[4][256])
#define L_X3   154256       // 256B pg partial exchange (f32[4][16])
#define LDS_BYTES 154512

__device__ __forceinline__ float sigf(float x) { return 1.f / (1.f + __expf(-x)); }
__device__ __forceinline__ float tanhfast(float x) { return 2.f / (1.f + __expf(-2.f * x)) - 1.f; }

__device__ __forceinline__ f32x4 MF(half8 a, half8 b, f32x4 c) {
  return __builtin_amdgcn_mfma_f32_16x16x32_f16(a, b, c, 0, 0, 0);
}

__device__ __forceinline__ u64 ald8(const f16* p) {
  return __hip_atomic_load((const u64*)p, __ATOMIC_RELAXED, __HIP_MEMORY_SCOPE_AGENT);
}
// A-frag load for MFMA chunk kk, k-group kg, row R from a PACKED4 buffer:
// k = kk*32 + kg*8 + j  ->  4-unit chunks (8kk+2kg) and (8kk+2kg+1)
__device__ __forceinline__ half8 aldchunk(const f16* base, int kk, int kg, int R) {
  int ch = 8 * kk + 2 * kg;
  union { u64 u[2]; half8 h; } x;
  x.u[0] = ald8(base + ((size_t)(ch * 64 + R) * 4));
  x.u[1] = ald8(base + ((size_t)((ch + 1) * 64 + R) * 4));
  return x.h;
}
__device__ __forceinline__ void ast4f(float* p, float v) {
  __hip_atomic_store((unsigned*)(void*)p, __float_as_uint(v), __ATOMIC_RELAXED, __HIP_MEMORY_SCOPE_AGENT);
}
// Pack 4 units of one row (from lanes c, c+16, c+32, c+48) into one 8B word and
// store coalesced: wave stores 16 rows x 8B = 128B. Call from all lanes of a wave.
__device__ __forceinline__ void store_act(f16* base, int w, int m, float hvf) {
  f16 hv = (f16)hvf;
  unsigned short hb; __builtin_memcpy(&hb, &hv, 2);
  int l = threadIdx.x & 63;
  int c_ = l & 15;
  int v1 = __shfl((int)hb, c_ + 16);
  int v2 = __shfl((int)hb, c_ + 32);
  int v3 = __shfl((int)hb, c_ + 48);
  if (l < 16) {
    int R = 16 * m + c_;
    u64 val = (u64)hb | ((u64)(unsigned short)v1 << 16)
            | ((u64)(unsigned short)v2 << 32) | ((u64)(unsigned short)v3 << 48);
    __hip_atomic_store((u64*)(base + ((size_t)(w * 64 + R) * 4)), val,
                       __ATOMIC_RELAXED, __HIP_MEMORY_SCOPE_AGENT);
  }
}

// -------- flat barrier: 16 group counters, direct 16-line poll --------
// Arrival: one relaxed fetch_add on group counter (w>>4). After k-th global
// barrier every counter == 16k (monotonic, no reset). Wait: wave 0 polls all
// 16 lines (lane&15) and tests __all(cnt >= 16e).
__device__ __forceinline__ void bar_arrive(char* bar, int w) {
  asm volatile("s_waitcnt vmcnt(0)" ::: "memory");   // this wave's stores at LLC
  __syncthreads();                                   // => all waves' stores done
  if (threadIdx.x == 0) {
    unsigned* cnt = (unsigned*)(bar + (size_t)(w >> 4) * 128);
    __hip_atomic_fetch_add(cnt, 1u, __ATOMIC_RELAXED, __HIP_MEMORY_SCOPE_AGENT);
  }
}
__device__ __forceinline__ void bar_wait(char* bar, unsigned e) {
  if (threadIdx.x < 64) {
    unsigned* cnt = (unsigned*)(bar + (size_t)(threadIdx.x & 15) * 128);
    unsigned tgt = e << 4;
    while (true) {
      unsigned v = __hip_atomic_load(cnt, __ATOMIC_RELAXED, __HIP_MEMORY_SCOPE_AGENT);
      if (__all((int)(v >= tgt))) break;
      __builtin_amdgcn_s_sleep(8);
    }
    asm volatile("" ::: "memory");    // compiler barrier; HW order via control dep
  }
  __syncthreads();
}

__global__ void init_state(const float* __restrict__ h1, const float* __restrict__ h2,
                           const float* __restrict__ pg0, const float* __restrict__ W1,
                           const float* __restrict__ b1, const float* __restrict__ b2,
                           char* __restrict__ ws) {
  int i = blockIdx.x * blockDim.x + threadIdx.x;  // 0..65535
  int R = i & 63;
  int U = i >> 6;
  f16* H1p = (f16*)(ws + WS_H1P);
  f16* H2p = (f16*)(ws + WS_H2P);
  int pidx = ((U >> 2) * 64 + R) * 4 + (U & 3);   // PACKED4
  H1p[pidx] = (f16)h1[(size_t)R * NH + U];   // parity-0 buffer
  H2p[pidx] = (f16)h2[(size_t)R * NH + U];
  if (i < 16384) {
    int u = i >> 6, r2 = i & 63;
    ((f16*)(ws + WS_PG0))[((u >> 2) * 64 + r2) * 4 + (u & 3)] = (f16)pg0[(size_t)r2 * NZ + u];
  }
  if (i < NH) {  // b1p = b1 + W1p @ b2
    float acc = b1[i];
    const float* wp = W1 + (size_t)i * (2 * NZ) + NZ;
    for (int mm = 0; mm < NZ; ++mm) acc = fmaf(wp[mm], b2[mm], acc);
    ((float*)(ws + WS_B1P))[i] = acc;
  }
  if (i < 8192) ((unsigned*)(ws + WS_BAR))[i] = 0u;
}

__global__ void prep_wfused(const float* __restrict__ W1, const float* __restrict__ W2,
                            char* __restrict__ ws) {
  int u = blockIdx.x >> 2;
  int j = ((blockIdx.x & 3) << 8) + threadIdx.x;
  const float* wp = W1 + (size_t)u * (2 * NZ) + NZ;
  float acc = 0.f;
  for (int mm = 0; mm < NZ; ++mm) acc = fmaf(wp[mm], W2[(size_t)mm * NH + j], acc);
  ((f16*)(ws + WS_WF))[(size_t)u * NH + j] = (f16)acc;
}

__global__ __launch_bounds__(NT, 1) void gen_persistent(
    const float* __restrict__ z,
    const float* __restrict__ W1, const float* __restrict__ b1,
    const float* __restrict__ Wih1, const float* __restrict__ Whh1,
    const float* __restrict__ bih1, const float* __restrict__ bhh1,
    const float* __restrict__ Wih2, const float* __restrict__ Whh2,
    const float* __restrict__ bih2, const float* __restrict__ bhh2,
    const float* __restrict__ W2, const float* __restrict__ b2,
    const float* __restrict__ c1in, const float* __restrict__ c2in,
    float* __restrict__ dout, char* __restrict__ ws)
{
  extern __shared__ char smem[];
  const int w = blockIdx.x;
  const int tid = threadIdx.x;
  const int w8 = tid >> 6;     // wave 0..7
  const int m = w8 & 3;        // batch-row block (rows 16m..16m+15)
  const int kh = w8 >> 2;      // K half: 0 = low, 1 = high
  const int l = tid & 63;
  const int c = l & 15;
  const int kg = l >> 4;

  f16* OutP = (f16*)(ws + WS_OUTP);
  f16* H1p = (f16*)(ws + WS_H1P);
  f16* H2p = (f16*)(ws + WS_H2P);
  const f16* Wf = (const f16*)(ws + WS_WF);
  const f16* Pg0p = (const f16*)(ws + WS_PG0);
  const float* b1p = (const float*)(ws + WS_B1P);
  char* bar = ws + WS_BAR;

  // ---- load this CU's weight slices into LDS (fp32 -> fp16), once ----
  for (int i = 0; i < 16; ++i) {
    int gi = i >> 2, uu = 4 * w + (i & 3);
    const float* s1i = Wih1 + (size_t)(gi * NH + uu) * NH;
    const float* s1h = Whh1 + (size_t)(gi * NH + uu) * NH;
    const float* s2i = Wih2 + (size_t)(gi * NH + uu) * NH;
    const float* s2h = Whh2 + (size_t)(gi * NH + uu) * NH;
    f16* d1 = (f16*)(smem + L_W1 + i * 4112);
    f16* d2 = (f16*)(smem + L_WP2 + i * 4112);
    for (int k = tid; k < NH; k += NT) {
      d1[k] = (f16)s1i[k]; d1[NH + k] = (f16)s1h[k];
      d2[k] = (f16)s2i[k]; d2[NH + k] = (f16)s2h[k];
    }
  }
  for (int i = 0; i < 4; ++i) {
    int uu = 4 * w + i;
    f16* d0 = (f16*)(smem + L_W0 + i * 2576);
    if (tid < 256) d0[tid] = (f16)W1[(size_t)uu * (2 * NZ) + tid];   // z part
    for (int k = tid; k < NH; k += NT) d0[NZ + k] = Wf[(size_t)uu * NH + k];
    f16* dp = (f16*)(smem + L_W1P + i * 528);
    if (tid < 256) dp[tid] = (f16)W1[(size_t)uu * (2 * NZ) + NZ + tid];  // W1p for t==0
  }
  {
    f16* dw2 = (f16*)(smem + L_W2);
    for (int k = tid; k < NH; k += NT) dw2[k] = (f16)W2[(size_t)w * NH + k];
  }
  __syncthreads();

  const int R = 16 * m + c;          // batch row
  const int U = 4 * w + kg;          // owned unit (kh==1 threads do gate math)
  const float b0fused = b1p[U];
  const float b0plain = b1[U];
  const float bi1 = bih1[U] + bhh1[U];
  const float bf1 = bih1[NH + U] + bhh1[NH + U];
  const float bg1 = bih1[2 * NH + U] + bhh1[2 * NH + U];
  const float bo1 = bih1[3 * NH + U] + bhh1[3 * NH + U];
  const float bi2 = bih2[U] + bhh2[U];
  const float bf2 = bih2[NH + U] + bhh2[NH + U];
  const float bg2 = bih2[2 * NH + U] + bhh2[2 * NH + U];
  const float bo2 = bih2[3 * NH + U] + bhh2[3 * NH + U];
  const float b2w = b2[w];

  float c1reg = c1in[(size_t)R * NH + U];
  float c2reg = c2in[(size_t)R * NH + U];
  float h1last = 0.f, h2last = 0.f;

  float* scr  = (float*)(smem + L_X) + m * 256;       // kh1 intra-wave gate exchange
  float* scr2 = (float*)(smem + L_X2) + m * 256;      // K-split partial (per row-block)
  float* scr3 = (float*)(smem + L_X3) + m * 16;       // pg partial
  const char* brow0 = smem + L_W0 + (c & 3) * 2576 + kg * 16;
  const char* brow2 = smem + L_W2 + kg * 16;
  const char* brow1 = smem + L_W1 + c * 4112 + kg * 16;
  const char* browp2 = smem + L_WP2 + c * 4112 + kg * 16;
  const char* browp0 = smem + L_W1P + (c & 3) * 528 + kg * 16;
  const float* zlane = z + (size_t)R * NS * NZ + kg * 8;

  for (int t = 0; t < NS; ++t) {
    const int par = t & 1;
    f16* h2prev = H2p + par * 65536;
    f16* h1prev = H1p + par * 65536;
    const unsigned eb = 3u * (unsigned)t;

    // ================= P0 =================
    f32x4 ao0 = {0.f, 0.f, 0.f, 0.f}, ao1 = ao0, ap0 = ao0, ap1 = ao0;
    if (t == 0) {
      if (kh == 0) {   // z part, all 8 chunks
        #pragma unroll
        for (int kk = 0; kk < 8; ++kk) {
          f32x4 f0 = *(const f32x4*)(zlane + kk * 32);
          f32x4 f1 = *(const f32x4*)(zlane + kk * 32 + 4);
          half8 a;
          a[0] = (f16)f0[0]; a[1] = (f16)f0[1]; a[2] = (f16)f0[2]; a[3] = (f16)f0[3];
          a[4] = (f16)f1[0]; a[5] = (f16)f1[1]; a[6] = (f16)f1[2]; a[7] = (f16)f1[3];
          half8 b = *(const half8*)(brow0 + kk * 64);
          if (kk & 1) ao1 = MF(a, b, ao1); else ao0 = MF(a, b, ao0);
        }
      } else {         // true prev_gen0 path through W1p (K=256 -> 8 chunks)
        #pragma unroll
        for (int kk = 0; kk < 8; ++kk) {
          half8 a = aldchunk(Pg0p, kk, kg, R);
          half8 b = *(const half8*)(browp0 + kk * 64);
          if (kk & 1) ao1 = MF(a, b, ao1); else ao0 = MF(a, b, ao0);
        }
      }
      bar_wait(bar, eb);
    } else {
      // ind0: z part, K split 4+4 chunks
      const float* zt = zlane + (size_t)t * NZ;
      #pragma unroll
      for (int i = 0; i < 4; ++i) {
        int kk = kh * 4 + i;
        f32x4 f0 = *(const f32x4*)(zt + kk * 32);
        f32x4 f1 = *(const f32x4*)(zt + kk * 32 + 4);
        half8 a;
        a[0] = (f16)f0[0]; a[1] = (f16)f0[1]; a[2] = (f16)f0[2]; a[3] = (f16)f0[3];
        a[4] = (f16)f1[0]; a[5] = (f16)f1[1]; a[6] = (f16)f1[2]; a[7] = (f16)f1[3];
        half8 b = *(const half8*)(brow0 + kk * 64);
        if (i & 1) ao1 = MF(a, b, ao1); else ao0 = MF(a, b, ao0);
      }
      bar_wait(bar, eb);
      // dep0: h2prev @ [Wfused | W2], K split 16+16
      #pragma unroll 8
      for (int i = 0; i < 16; ++i) {
        int kk = kh * 16 + i;
        half8 a = aldchunk(h2prev, kk, kg, R);
        half8 bwf = *(const half8*)(brow0 + 512 + kk * 64);
        half8 bw2 = *(const half8*)(brow2 + kk * 64);
        if (i & 1) { ao1 = MF(a, bwf, ao1); ap1 = MF(a, bw2, ap1); }
        else       { ao0 = MF(a, bwf, ao0); ap0 = MF(a, bw2, ap0); }
      }
    }
    f32x4 Dp;
    {
      f32x4 D = ao0 + ao1;
      Dp = ap0 + ap1;
      if (kh == 0) {
        if (c < 4) {
          #pragma unroll
          for (int v = 0; v < 4; ++v) scr2[c * 16 + kg * 4 + v] = D[v];
        }
        if (c == 0 && t > 0) {
          #pragma unroll
          for (int v = 0; v < 4; ++v) scr3[kg * 4 + v] = Dp[v];
        }
      }
      __syncthreads();
      if (kh == 1) {
        if (c < 4) {
          #pragma unroll
          for (int v = 0; v < 4; ++v) scr[c * 16 + kg * 4 + v] = D[v] + scr2[c * 16 + kg * 4 + v];
        }
        float pre = scr[kg * 16 + c] + ((t == 0) ? b0plain : b0fused);
        store_act(OutP, w, m, fmaxf(pre, 0.f));
      }
    }
    bar_arrive(bar, w);   // completes epoch 3t+1
    // deferred lazy pg(t-1) store — out of the drain-critical path
    if (kh == 1 && t > 0 && c == 0) {
      #pragma unroll
      for (int v = 0; v < 4; ++v) {
        int Rp = 16 * m + kg * 4 + v;
        ast4f(&dout[((size_t)Rp * NS + (t - 1)) * NZ + w], Dp[v] + scr3[kg * 4 + v] + b2w);
      }
    }

    // ================= P1 =================
    f32x4 g0 = {0.f, 0.f, 0.f, 0.f}, g1 = g0;
    #pragma unroll 8
    for (int i = 0; i < 16; ++i) {   // ind1: h1prev @ Whh1 (one step old)
      int kk = kh * 16 + i;
      half8 a = aldchunk(h1prev, kk, kg, R);
      half8 b = *(const half8*)(brow1 + 2048 + kk * 64);
      if (i & 1) g1 = MF(a, b, g1); else g0 = MF(a, b, g0);
    }
    bar_wait(bar, eb + 1);
    #pragma unroll 8
    for (int i = 0; i < 16; ++i) {   // dep1: out @ Wih1
      int kk = kh * 16 + i;
      half8 a = aldchunk(OutP, kk, kg, R);
      half8 b = *(const half8*)(brow1 + kk * 64);
      if (i & 1) g1 = MF(a, b, g1); else g0 = MF(a, b, g0);
    }
    {
      f32x4 D = g0 + g1;
      if (kh == 0) {
        #pragma unroll
        for (int v = 0; v < 4; ++v) scr2[c * 16 + kg * 4 + v] = D[v];
      }
      __syncthreads();
      if (kh == 1) {
        #pragma unroll
        for (int v = 0; v < 4; ++v) scr[c * 16 + kg * 4 + v] = D[v] + scr2[c * 16 + kg * 4 + v];
        float ai = scr[kg * 16 + c];
        float af = scr[(4 + kg) * 16 + c];
        float ag = scr[(8 + kg) * 16 + c];
        float aoo = scr[(12 + kg) * 16 + c];
        float iv = sigf(ai + bi1), fv = sigf(af + bf1);
        float gv = tanhfast(ag + bg1), ov = sigf(aoo + bo1);
        float cn = fmaf(fv, c1reg, iv * gv);
        c1reg = cn;
        float hv = ov * tanhfast(cn);
        h1last = hv;
        store_act(H1p + (par ^ 1) * 65536, w, m, hv);
      }
    }
    bar_arrive(bar, w);   // completes epoch 3t+2

    // ================= P2 =================
    f32x4 q0 = {0.f, 0.f, 0.f, 0.f}, q1 = q0;
    #pragma unroll 8
    for (int i = 0; i < 16; ++i) {   // ind2: h2prev @ Whh2
      int kk = kh * 16 + i;
      half8 a = aldchunk(h2prev, kk, kg, R);
      half8 b = *(const half8*)(browp2 + 2048 + kk * 64);
      if (i & 1) q1 = MF(a, b, q1); else q0 = MF(a, b, q0);
    }
    bar_wait(bar, eb + 2);
    {
      f16* h1new = H1p + (par ^ 1) * 65536;
      #pragma unroll 8
      for (int i = 0; i < 16; ++i) {  // dep2: h1new @ Wih2
        int kk = kh * 16 + i;
        half8 a = aldchunk(h1new, kk, kg, R);
        half8 b = *(const half8*)(browp2 + kk * 64);
        if (i & 1) q1 = MF(a, b, q1); else q0 = MF(a, b, q0);
      }
    }
    {
      f32x4 D = q0 + q1;
      if (kh == 0) {
        #pragma unroll
        for (int v = 0; v < 4; ++v) scr2[c * 16 + kg * 4 + v] = D[v];
      }
      __syncthreads();
      if (kh == 1) {
        #pragma unroll
        for (int v = 0; v < 4; ++v) scr[c * 16 + kg * 4 + v] = D[v] + scr2[c * 16 + kg * 4 + v];
        float ai = scr[kg * 16 + c];
        float af = scr[(4 + kg) * 16 + c];
        float ag = scr[(8 + kg) * 16 + c];
        float aoo = scr[(12 + kg) * 16 + c];
        float iv = sigf(ai + bi2), fv = sigf(af + bf2);
        float gv = tanhfast(ag + bg2), ov = sigf(aoo + bo2);
        float cn = fmaf(fv, c2reg, iv * gv);
        c2reg = cn;
        float hv = ov * tanhfast(cn);
        h2last = hv;
        store_act(H2p + (par ^ 1) * 65536, w, m, hv);
      }
    }
    bar_arrive(bar, w);   // completes epoch 3t+3
  }

  // ---------- tail: pg for t=511 from final h2 (parity 0) ----------
  bar_wait(bar, 3u * NS);
  {
    f32x4 ap0t = {0.f, 0.f, 0.f, 0.f}, ap1t = ap0t;
    #pragma unroll 8
    for (int i = 0; i < 16; ++i) {
      int kk = kh * 16 + i;
      half8 a = aldchunk(H2p, kk, kg, R);
      half8 b = *(const half8*)(brow2 + kk * 64);
      if (i & 1) ap1t = MF(a, b, ap1t); else ap0t = MF(a, b, ap0t);
    }
    f32x4 Dp = ap0t + ap1t;
    if (kh == 0 && c == 0) {
      #pragma unroll
      for (int v = 0; v < 4; ++v) scr3[kg * 4 + v] = Dp[v];
    }
    __syncthreads();
    if (kh == 1 && c == 0) {
      #pragma unroll
      for (int v = 0; v < 4; ++v) {
        int Rp = 16 * m + kg * 4 + v;
        dout[((size_t)Rp * NS + (NS - 1)) * NZ + w] = Dp[v] + scr3[kg * 4 + v] + b2w;
      }
    }
  }

  // ---------- final states (kh1 threads own (U,R), all in registers) ----------
  if (kh == 1) {
    float* o = dout + (size_t)NB * NS * NZ;
    o[(size_t)R * NH + U] = h1last;
    o[(size_t)NB * NH + (size_t)R * NH + U] = c1reg;
    o[2 * (size_t)NB * NH + (size_t)R * NH + U] = h2last;
    o[3 * (size_t)NB * NH + (size_t)R * NH + U] = c2reg;
  }
}

extern "C" void kernel_launch(void* const* d_in, const int* in_sizes, int n_in,
                              void* d_out, int out_size, void* d_ws, size_t ws_size,
                              hipStream_t stream) {
  const float* z    = (const float*)d_in[0];
  const float* pg0  = (const float*)d_in[1];
  const float* h1   = (const float*)d_in[2];
  const float* c1   = (const float*)d_in[3];
  const float* h2   = (const float*)d_in[4];
  const float* c2   = (const float*)d_in[5];
  const float* W1   = (const float*)d_in[6];
  const float* b1   = (const float*)d_in[7];
  const float* Wih1 = (const float*)d_in[8];
  const float* Whh1 = (const float*)d_in[9];
  const float* bih1 = (const float*)d_in[10];
  const float* bhh1 = (const float*)d_in[11];
  const float* Wih2 = (const float*)d_in[12];
  const float* Whh2 = (const float*)d_in[13];
  const float* bih2 = (const float*)d_in[14];
  const float* bhh2 = (const float*)d_in[15];
  const float* W2   = (const float*)d_in[16];
  const float* b2   = (const float*)d_in[17];
  char* ws = (char*)d_ws;
  float* out = (float*)d_out;

  hipLaunchKernelGGL(init_state, dim3(256), dim3(256), 0, stream,
                     h1, h2, pg0, W1, b1, b2, ws);
  hipLaunchKernelGGL(prep_wfused, dim3(4096), dim3(256), 0, stream, W1, W2, ws);
  hipLaunchKernelGGL(gen_persistent, dim3(NWG), dim3(NT), LDS_BYTES, stream,
                     z, W1, b1, Wih1, Whh1, bih1, bhh1, Wih2, Whh2, bih2, bhh2, W2, b2,
                     c1, c2, out, ws);
}